// Round 5
// baseline (2163.787 us; speedup 1.0000x reference)
//
#include <hip/hip_runtime.h>
#include <math.h>

// Problem constants
#define NN 65536   // nodes
#define GG 128     // graphs
#define LL 512     // nodes per graph
#define DD 128     // feature dim
#define EE 262144  // edges
#define NSTEPS 6
#define CC 256     // concat dim
#define L1 510     // after k=3 valid conv
#define P1 254     // after pool(3,2)
#define P2 127     // after pool(2,2)

typedef __attribute__((ext_vector_type(8))) short s8bf;   // 8 bf16 in 4 VGPRs
typedef __attribute__((ext_vector_type(4))) float f4acc;  // MFMA accumulator

// fp32 -> bf16 (RNE) and back, as raw ushort
__device__ __forceinline__ unsigned short f2bf(float x) {
  unsigned u = __float_as_uint(x);
  unsigned r = u + 0x7FFFu + ((u >> 16) & 1u);
  return (unsigned short)(r >> 16);
}
__device__ __forceinline__ float bf2f(unsigned short h) {
  return __uint_as_float(((unsigned)h) << 16);
}
__device__ __forceinline__ unsigned short f2bf_sel(float x, int lo_sel) {
  unsigned short hi = f2bf(x);
  if (!lo_sel) return hi;
  return f2bf(x - bf2f(hi));
}
__device__ __forceinline__ uint2 pack4bf(float4 v, int lo_sel) {
  unsigned short s0 = f2bf_sel(v.x, lo_sel), s1 = f2bf_sel(v.y, lo_sel);
  unsigned short s2 = f2bf_sel(v.z, lo_sel), s3 = f2bf_sel(v.w, lo_sel);
  uint2 pk; pk.x = (unsigned)s0 | ((unsigned)s1 << 16);
  pk.y = (unsigned)s2 | ((unsigned)s3 << 16);
  return pk;
}

// ---------------------------------------------------------------------------
// prep: all weights to bf16 hi/lo in MFMA layouts.
// ---------------------------------------------------------------------------
__global__ __launch_bounds__(256) void k_prep(
    const float* __restrict__ wih, const float* __restrict__ whh,
    const float* __restrict__ gw,
    const float* __restrict__ w1, const float* __restrict__ wc1,
    const float* __restrict__ w2, const float* __restrict__ wc2,
    unsigned short* __restrict__ wihCh, unsigned short* __restrict__ wihCl,
    unsigned short* __restrict__ whhCh, unsigned short* __restrict__ whhCl,
    unsigned short* __restrict__ gwTh, unsigned short* __restrict__ gwTl,
    unsigned short* __restrict__ c1h, unsigned short* __restrict__ c1l,
    unsigned short* __restrict__ cc1h, unsigned short* __restrict__ cc1l,
    unsigned short* __restrict__ c2h, unsigned short* __restrict__ c2l,
    unsigned short* __restrict__ cc2h, unsigned short* __restrict__ cc2l) {
  int i = blockIdx.x * 256 + threadIdx.x;
  if (i < 49152) {  // GRU weights, elementwise hi/lo (already [384][128])
    float v = wih[i];
    unsigned short h_ = f2bf(v);
    wihCh[i] = h_; wihCl[i] = f2bf(v - bf2f(h_));
    float u = whh[i];
    unsigned short h2 = f2bf(u);
    whhCh[i] = h2; whhCl[i] = f2bf(u - bf2f(h2));
  }
  if (i < 98304) {  // gwT: i = s*16384 + col*128 + k
    int s = i >> 14; int r = i & 16383; int c = r >> 7; int k = r & 127;
    float v = gw[(s << 14) + k * 128 + c];
    unsigned short h_ = f2bf(v);
    gwTh[i] = h_; gwTl[i] = f2bf(v - bf2f(h_));
  }
  if (i < 49152) {  // c1: i = (tap*128+co)*128+ci ; src w1[co][ci][tap]
    int ci = i & 127; int r = i >> 7; int co = r & 127; int tap = r >> 7;
    float v = w1[(co * 128 + ci) * 3 + tap];
    unsigned short h_ = f2bf(v);
    c1h[i] = h_; c1l[i] = f2bf(v - bf2f(h_));
  }
  if (i < 196608) {  // cc1: i = (tap*256+co)*256+ci ; src wc1[co][ci][tap]
    int ci = i & 255; int r = i >> 8; int co = r & 255; int tap = r >> 8;
    float v = wc1[(co * 256 + ci) * 3 + tap];
    unsigned short h_ = f2bf(v);
    cc1h[i] = h_; cc1l[i] = f2bf(v - bf2f(h_));
  }
  if (i < 16384) {  // c2: identity layout [co][ci]
    float v = w2[i];
    unsigned short h_ = f2bf(v);
    c2h[i] = h_; c2l[i] = f2bf(v - bf2f(h_));
  }
  if (i < 65536) {  // cc2: identity layout [co][ci]
    float v = wc2[i];
    unsigned short h_ = f2bf(v);
    cc2h[i] = h_; cc2l[i] = f2bf(v - bf2f(h_));
  }
}

// ---------------------------------------------------------------------------
// x -> bf16 hi/lo planes (once per launch); 8 elems/thread, 16B stores.
// ---------------------------------------------------------------------------
__global__ __launch_bounds__(256) void k_castx(const float* __restrict__ x,
                                               unsigned short* __restrict__ xH,
                                               unsigned short* __restrict__ xL) {
  int i = blockIdx.x * 256 + threadIdx.x;  // 1,048,576 threads x 8 elems
  const float4* x4 = (const float4*)x;
  float4 a = x4[i * 2 + 0];
  float4 b = x4[i * 2 + 1];
  uint2 ha = pack4bf(a, 0), hb = pack4bf(b, 0);
  uint2 la = pack4bf(a, 1), lb = pack4bf(b, 1);
  uint4 hv; hv.x = ha.x; hv.y = ha.y; hv.z = hb.x; hv.w = hb.y;
  uint4 lv; lv.x = la.x; lv.y = la.y; lv.z = lb.x; lv.w = lb.y;
  *(uint4*)&xH[i * 8] = hv;
  *(uint4*)&xL[i * 8] = lv;
}

// ---------------------------------------------------------------------------
// CSR build (by dst) so the per-step aggregation is an atomic-free gather
// ---------------------------------------------------------------------------
__global__ __launch_bounds__(256) void k_hist(const int* __restrict__ dst, int* __restrict__ cnt) {
  int e = blockIdx.x * 256 + threadIdx.x;
  if (e < EE) atomicAdd(&cnt[dst[e]], 1);
}

__global__ __launch_bounds__(1024) void k_scan(const int* __restrict__ cnt,
                                               int* __restrict__ rowptr,
                                               int* __restrict__ cursor) {
  __shared__ int part[1024];
  int t = threadIdx.x;
  int base = t * 64;
  int s = 0;
  for (int i = 0; i < 64; i++) s += cnt[base + i];
  part[t] = s;
  __syncthreads();
  for (int off = 1; off < 1024; off <<= 1) {
    int v = part[t];
    int u = (t >= off) ? part[t - off] : 0;
    __syncthreads();
    part[t] = v + u;
    __syncthreads();
  }
  int run = part[t] - s;  // exclusive prefix of this chunk
  for (int i = 0; i < 64; i++) {
    rowptr[base + i] = run;
    cursor[base + i] = run;
    run += cnt[base + i];
  }
  if (t == 1023) rowptr[NN] = run;
}

__global__ __launch_bounds__(256) void k_fill(const int* __restrict__ src,
                                              const int* __restrict__ dst,
                                              const float* __restrict__ ew,
                                              int* __restrict__ cursor,
                                              int* __restrict__ col,
                                              float* __restrict__ wgt) {
  int e = blockIdx.x * 256 + threadIdx.x;
  if (e < EE) {
    int d = dst[e];
    int p = atomicAdd(&cursor[d], 1);
    col[p] = src[e];
    wgt[p] = ew[e];
  }
}

// ---------------------------------------------------------------------------
// m = h @ W via split-bf16 MFMA; A comes in as pre-split bf16 hi/lo planes,
// staging is a pure 16B copy. Pass order: hh, hl, lh.
// (R1 structure; launch_bounds (256,8): VGPR=64 measured -> 8 blocks/CU.)
// ---------------------------------------------------------------------------
__global__ __launch_bounds__(256, 8) void k_gemm_mfma(
    const unsigned short* __restrict__ Ah, const unsigned short* __restrict__ Al,
    const unsigned short* __restrict__ Wh, const unsigned short* __restrict__ Wl,
    float* __restrict__ Cout) {
  __shared__ __attribute__((aligned(16))) unsigned short As[64 * 136];
  int t = threadIdx.x;
  int r0 = blockIdx.x * 64;
  int wv = t >> 6, lane = t & 63;
  int ln = lane & 15, q = lane >> 4;
  f4acc acc[4][2];
#pragma unroll
  for (int mt = 0; mt < 4; mt++)
#pragma unroll
    for (int nt = 0; nt < 2; nt++) acc[mt][nt] = (f4acc)0.f;

  for (int p = 0; p < 3; p++) {
    if (p != 1) {  // stage A full K (hi at p0, lo at p2): 4 exact 16B copies/thread
      const unsigned short* S = (p == 2) ? Al : Ah;
      if (p) __syncthreads();
#pragma unroll
      for (int it = 0; it < 4; it++) {
        int v8 = it * 256 + t;
        int row = v8 >> 4, k = (v8 & 15) * 8;
        *(uint4*)&As[row * 136 + k] = *(const uint4*)&S[(r0 + row) * 128 + k];
      }
      __syncthreads();
    }
    const unsigned short* W = (p == 1) ? Wl : Wh;
#pragma unroll
    for (int k0 = 0; k0 < 128; k0 += 32) {
      s8bf af[4], bf[2];
#pragma unroll
      for (int nt = 0; nt < 2; nt++)
        bf[nt] = *(const s8bf*)&W[(wv * 32 + nt * 16 + ln) * 128 + k0 + q * 8];
#pragma unroll
      for (int mt = 0; mt < 4; mt++)
        af[mt] = *(const s8bf*)&As[(mt * 16 + ln) * 136 + k0 + q * 8];
#pragma unroll
      for (int mt = 0; mt < 4; mt++)
#pragma unroll
        for (int nt = 0; nt < 2; nt++)
          acc[mt][nt] = __builtin_amdgcn_mfma_f32_16x16x32_bf16(af[mt], bf[nt], acc[mt][nt], 0, 0, 0);
    }
  }
#pragma unroll
  for (int mt = 0; mt < 4; mt++)
#pragma unroll
    for (int nt = 0; nt < 2; nt++)
#pragma unroll
      for (int reg = 0; reg < 4; reg++) {
        int r = r0 + mt * 16 + q * 4 + reg;
        Cout[r * 128 + wv * 32 + nt * 16 + ln] = acc[mt][nt][reg];
      }
}

// ---------------------------------------------------------------------------
// agg[n,:] = sum over in-edges of m[src,:]*w.  Emits agg directly as bf16
// hi/lo planes (identical bits to what the GRU staging used to compute).
// ---------------------------------------------------------------------------
__global__ __launch_bounds__(256) void k_gather(const float* __restrict__ m,
                                                const int* __restrict__ rowptr,
                                                const int* __restrict__ col,
                                                const float* __restrict__ wgt,
                                                unsigned short* __restrict__ aggH,
                                                unsigned short* __restrict__ aggL) {
  int t = threadIdx.x;
  int n = blockIdx.x * 8 + (t >> 5);
  int c4 = t & 31;
  const float4* m4 = (const float4*)m;
  int s0 = rowptr[n], s1 = rowptr[n + 1];
  float ax = 0.f, ay = 0.f, az = 0.f, aw = 0.f;
  int e = s0;
  for (; e + 2 <= s1; e += 2) {
    int cA = col[e], cB = col[e + 1];
    float wA = wgt[e], wB = wgt[e + 1];
    float4 vA = m4[cA * 32 + c4];
    float4 vB = m4[cB * 32 + c4];
    ax += vA.x * wA + vB.x * wB;
    ay += vA.y * wA + vB.y * wB;
    az += vA.z * wA + vB.z * wB;
    aw += vA.w * wA + vB.w * wB;
  }
  if (e < s1) {
    int cA = col[e];
    float wA = wgt[e];
    float4 vA = m4[cA * 32 + c4];
    ax += vA.x * wA; ay += vA.y * wA; az += vA.z * wA; aw += vA.w * wA;
  }
  unsigned short h0 = f2bf(ax), h1 = f2bf(ay), h2 = f2bf(az), h3 = f2bf(aw);
  unsigned short l0 = f2bf(ax - bf2f(h0)), l1 = f2bf(ay - bf2f(h1));
  unsigned short l2 = f2bf(az - bf2f(h2)), l3 = f2bf(aw - bf2f(h3));
  uint2 hpk, lpk;
  hpk.x = (unsigned)h0 | ((unsigned)h1 << 16); hpk.y = (unsigned)h2 | ((unsigned)h3 << 16);
  lpk.x = (unsigned)l0 | ((unsigned)l1 << 16); lpk.y = (unsigned)l2 | ((unsigned)l3 << 16);
  int base = n * 128 + c4 * 4;
  *(uint2*)&aggH[base] = hpk;
  *(uint2*)&aggL[base] = lpk;
}

// ---------------------------------------------------------------------------
// Fused dual GEMM + GRU via split-bf16 MFMA; both A matrices arrive as bf16
// hi/lo planes -> staging is 8 exact 16B copies/thread. Output bf16 hi/lo
// planes only; hold reconstructed hi+lo. NOT in-place.
// grid (1024, 4): block = 64 rows x 32 d; waves 2x2 (wr row-half, wc d-half).
// acc halves to 48 regs -> ~118 VGPR -> 4 blocks/CU (was 2 at acc=96).
// ---------------------------------------------------------------------------
__global__ __launch_bounds__(256, 3) void k_gru_mfma(
    const unsigned short* __restrict__ aggH, const unsigned short* __restrict__ aggL,
    const unsigned short* __restrict__ hinH, const unsigned short* __restrict__ hinL,
    const unsigned short* __restrict__ wihCh, const unsigned short* __restrict__ wihCl,
    const unsigned short* __restrict__ whhCh, const unsigned short* __restrict__ whhCl,
    const float* __restrict__ bih, const float* __restrict__ bhh,
    unsigned short* __restrict__ houtH, unsigned short* __restrict__ houtL) {
  __shared__ __attribute__((aligned(16))) unsigned short As[2 * 64 * 136];  // [mat][row][k]
  int t = threadIdx.x;
  int r0 = blockIdx.x * 64;
  int d0 = blockIdx.y * 32;
  int wv = t >> 6, lane = t & 63;
  int ln = lane & 15, q = lane >> 4;
  int wr = wv & 1, wc = wv >> 1;
  f4acc acc[2][6];
#pragma unroll
  for (int mt = 0; mt < 2; mt++)
#pragma unroll
    for (int tg = 0; tg < 6; tg++) acc[mt][tg] = (f4acc)0.f;

  for (int p = 0; p < 3; p++) {
    if (p != 1) {  // stage both A mats full K: hi at p0, lo at p2
      const unsigned short* s0 = (p == 2) ? aggL : aggH;
      const unsigned short* s1 = (p == 2) ? hinL : hinH;
      if (p) __syncthreads();
#pragma unroll
      for (int it = 0; it < 8; it++) {
        int v8 = it * 256 + t;          // 0..2047
        int mat = v8 >> 10;
        int row = (v8 >> 4) & 63, k = (v8 & 15) * 8;
        const unsigned short* S = mat ? s1 : s0;
        *(uint4*)&As[mat * 8704 + row * 136 + k] = *(const uint4*)&S[(r0 + row) * 128 + k];
      }
      __syncthreads();
    }
    const unsigned short* wx = (p == 1) ? wihCl : wihCh;
    const unsigned short* wh = (p == 1) ? whhCl : whhCh;
#pragma unroll
    for (int k0 = 0; k0 < 128; k0 += 32) {
      s8bf af[2][2], bfr[6];
#pragma unroll
      for (int tg = 0; tg < 6; tg++) {
        int gate = (tg < 3) ? tg : tg - 3;
        const unsigned short* W = (tg < 3) ? wx : wh;
        bfr[tg] = *(const s8bf*)&W[(gate * 128 + d0 + wc * 16 + ln) * 128 + k0 + q * 8];
      }
#pragma unroll
      for (int mat = 0; mat < 2; mat++)
#pragma unroll
        for (int mt = 0; mt < 2; mt++)
          af[mat][mt] = *(const s8bf*)&As[mat * 8704 + (wr * 32 + mt * 16 + ln) * 136 + k0 + q * 8];
#pragma unroll
      for (int mt = 0; mt < 2; mt++)
#pragma unroll
        for (int tg = 0; tg < 6; tg++)
          acc[mt][tg] = __builtin_amdgcn_mfma_f32_16x16x32_bf16(
              af[tg < 3 ? 0 : 1][mt], bfr[tg], acc[mt][tg], 0, 0, 0);
    }
  }
  int d = d0 + wc * 16 + ln;
  float bi0 = bih[d], bi1 = bih[128 + d], bi2 = bih[256 + d];
  float bh0 = bhh[d], bh1 = bhh[128 + d], bh2 = bhh[256 + d];
#pragma unroll
  for (int mt = 0; mt < 2; mt++) {
#pragma unroll
    for (int reg = 0; reg < 4; reg++) {
      int r = r0 + wr * 32 + mt * 16 + q * 4 + reg;
      int idx = r * 128 + d;
      float hold = bf2f(hinH[idx]) + bf2f(hinL[idx]);
      float xr = acc[mt][0][reg] + bi0;
      float xz = acc[mt][1][reg] + bi1;
      float xn = acc[mt][2][reg] + bi2;
      float hr = acc[mt][3][reg] + bh0;
      float hz = acc[mt][4][reg] + bh1;
      float hn = acc[mt][5][reg] + bh2;
      float rr = 1.f / (1.f + expf(-(xr + hr)));
      float zz = 1.f / (1.f + expf(-(xz + hz)));
      float nnv = tanhf(xn + rr * hn);
      float hv = (1.f - zz) * nnv + zz * hold;
      unsigned short hh = f2bf(hv);
      houtH[idx] = hh;
      houtL[idx] = f2bf(hv - bf2f(hh));
    }
  }
}

// ---------------------------------------------------------------------------
// Generic implicit-GEMM conv via split-bf16 MFMA. (R1-exact structure —
// measured best: full-K staging, 1-deep B prefetch, 64x128 block.)
// Inputs pre-split bf16 hi/lo planes (plane A ch<WA, plane B ch>=WA).
// Weights [tap][co][ci] bf16 hi/lo. Output [g][Lco][CIN] f32 + per-co stats.
// Block: 64 l-rows x 128 co; grid (ceil(Lco/64), CIN/128, G).
// ---------------------------------------------------------------------------
template<int CIN, int TAPS, int WA>
__global__ __launch_bounds__(256, 4) void k_conv_mfma(
    const unsigned short* __restrict__ hiA, const unsigned short* __restrict__ hiB,
    const unsigned short* __restrict__ loA, const unsigned short* __restrict__ loB,
    const unsigned short* __restrict__ Wh, const unsigned short* __restrict__ Wl,
    const float* __restrict__ bias, float* __restrict__ out,
    float* __restrict__ stats, int Lin, int Lco) {
  constexpr int APAD = CIN + 8;
  constexpr int ROWS = 64 + TAPS - 1;
  constexpr int NCH = CIN / 32;
  constexpr int TOT8 = ROWS * CIN / 8;       // 16B chunks to stage
  constexpr int NIT = (TOT8 + 255) / 256;
  constexpr int NINNER = TAPS * NCH;
  __shared__ __attribute__((aligned(16))) unsigned short As[ROWS * APAD];
  __shared__ float sred[256];
  const int g = blockIdx.z, co0 = blockIdx.y * 128, l0 = blockIdx.x * 64;
  const int t = threadIdx.x;
  const int wv = t >> 6, lane = t & 63, ln = lane & 15, q = lane >> 4;
  f4acc acc[4][2];
#pragma unroll
  for (int mt = 0; mt < 4; mt++)
#pragma unroll
    for (int nt = 0; nt < 2; nt++) acc[mt][nt] = (f4acc)0.f;

  // pass order: (Ah,Bh), (Ah,Bl), (Al,Bh)
  for (int p = 0; p < 3; p++) {
    if (p != 1) {
      const unsigned short* pA = (p == 2) ? loA : hiA;
      const unsigned short* pB = (p == 2) ? loB : hiB;
      if (p) __syncthreads();
#pragma unroll
      for (int it = 0; it < NIT; it++) {
        int v8 = it * 256 + t;
        if (NIT * 256 == TOT8 || v8 < TOT8) {
          int row = (v8 * 8) / CIN, ch = (v8 * 8) % CIN;
          int lr = l0 + row; if (lr > Lin - 1) lr = Lin - 1;
          uint4 v;
          if (ch < WA) v = *(const uint4*)&pA[(g * Lin + lr) * WA + ch];
          else         v = *(const uint4*)&pB[(g * Lin + lr) * WA + ch - WA];
          *(uint4*)&As[row * APAD + ch] = v;
        }
      }
      __syncthreads();
    }
    const unsigned short* W = (p == 1) ? Wl : Wh;
    // flat (tap, ch) loop with 1-deep B prefetch (B loads are the latency pole)
    s8bf bcur[2], bnxt[2];
#pragma unroll
    for (int nt = 0; nt < 2; nt++)
      bcur[nt] = *(const s8bf*)&W[(co0 + wv * 32 + nt * 16 + ln) * CIN + q * 8];
#pragma unroll
    for (int it = 0; it < NINNER; it++) {
      const int tap = it / NCH, ch = it % NCH;
      if (it + 1 < NINNER) {
        const int ntap = (it + 1) / NCH, nch = (it + 1) % NCH;
#pragma unroll
        for (int nt = 0; nt < 2; nt++)
          bnxt[nt] = *(const s8bf*)&W[(ntap * CIN + co0 + wv * 32 + nt * 16 + ln) * CIN + nch * 32 + q * 8];
      }
      const int c0 = ch * 32;
      s8bf af[4];
#pragma unroll
      for (int mt = 0; mt < 4; mt++)
        af[mt] = *(const s8bf*)&As[(mt * 16 + ln + tap) * APAD + c0 + q * 8];
#pragma unroll
      for (int mt = 0; mt < 4; mt++)
#pragma unroll
        for (int nt = 0; nt < 2; nt++)
          acc[mt][nt] = __builtin_amdgcn_mfma_f32_16x16x32_bf16(af[mt], bcur[nt], acc[mt][nt], 0, 0, 0);
      if (it + 1 < NINNER) { bcur[0] = bnxt[0]; bcur[1] = bnxt[1]; }
    }
  }
  // epilogue: bias, store [g][l][co], per-co sum/sumsq
  sred[t] = 0.f;
  __syncthreads();
#pragma unroll
  for (int nt = 0; nt < 2; nt++) {
    int cl = wv * 32 + nt * 16 + ln;
    int co = co0 + cl;
    float bv = bias[co];
    float s = 0.f, s2 = 0.f;
#pragma unroll
    for (int mt = 0; mt < 4; mt++)
#pragma unroll
      for (int reg = 0; reg < 4; reg++) {
        int l = l0 + mt * 16 + q * 4 + reg;
        if (l < Lco) {
          float v = acc[mt][nt][reg] + bv;
          out[(g * Lco + l) * CIN + co] = v;
          s += v; s2 += v * v;
        }
      }
    atomicAdd(&sred[cl], s);
    atomicAdd(&sred[128 + cl], s2);
  }
  __syncthreads();
  if (t < 128) atomicAdd(&stats[co0 + t], sred[t]);
  else atomicAdd(&stats[CIN + co0 + (t - 128)], sred[t]);
}

// ---------------------------------------------------------------------------
// BN(training stats) -> ReLU -> maxpool(pk, stride 2); l-major both sides.
// PLANES=true: emit bf16 hi/lo planes (for 1x1 conv input);
// PLANES=false: emit f32 (for k_final).
// ---------------------------------------------------------------------------
template<bool PLANES>
__global__ __launch_bounds__(256) void k_bnpool(const float* __restrict__ in,
                                                float* __restrict__ outF,
                                                unsigned short* __restrict__ outH,
                                                unsigned short* __restrict__ outL,
                                                const float* __restrict__ stats,
                                                const float* __restrict__ gamma,
                                                const float* __restrict__ beta,
                                                int Cch, int LinC, int Lout, int pk) {
  int idx = blockIdx.x * 256 + threadIdx.x;
  int total = GG * Cch * Lout;
  if (idx >= total) return;
  int c = idx & (Cch - 1);
  int r = idx / Cch;
  int p = r % Lout;
  int g = r / Lout;
  float cntf = (float)(GG * LinC);
  float mean = stats[c] / cntf;
  float var = stats[Cch + c] / cntf - mean * mean;
  float inv = rsqrtf(var + 1e-5f) * gamma[c];
  float sh = beta[c] - mean * inv;
  const float* base = &in[((g * LinC) + 2 * p) * Cch + c];
  float m = 0.f;  // relu output >= 0
  for (int k = 0; k < pk; k++) {
    float v = fmaxf(base[k * Cch] * inv + sh, 0.f);
    m = fmaxf(m, v);
  }
  int o = (g * Lout + p) * Cch + c;
  if (PLANES) {
    unsigned short hh = f2bf(m);
    outH[o] = hh;
    outL[o] = f2bf(m - bf2f(hh));
  } else {
    outF[o] = m;
  }
}

// ---------------------------------------------------------------------------
// final: Y2 [g][127][128], Z2 [g][127][256] l-major f32
// ---------------------------------------------------------------------------
__global__ __launch_bounds__(128) void k_final(const float* __restrict__ Y2,
                                               const float* __restrict__ Z2,
                                               const float* __restrict__ myw,
                                               const float* __restrict__ myb,
                                               const float* __restrict__ mzw,
                                               const float* __restrict__ mzb,
                                               float* __restrict__ outp) {
  __shared__ float red0[128];
  __shared__ float red1[128];
  int g = blockIdx.x;
  int t = threadIdx.x;
  float y0 = myb[0], y1 = myb[1], z0 = mzb[0], z1 = mzb[1];
  if (t < P2) {
    const float* yb = &Y2[(g * P2 + t) * 128];
    for (int c = 0; c < 128; c++) {
      float v = yb[c];
      y0 += v * myw[c];
      y1 += v * myw[128 + c];
    }
    const float* zb = &Z2[(g * P2 + t) * 256];
    for (int c = 0; c < 256; c++) {
      float v = zb[c];
      z0 += v * mzw[c];
      z1 += v * mzw[256 + c];
    }
  }
  red0[t] = (t < P2) ? y0 * z0 : 0.f;
  red1[t] = (t < P2) ? y1 * z1 : 0.f;
  __syncthreads();
  for (int off = 64; off > 0; off >>= 1) {
    if (t < off) {
      red0[t] += red0[t + off];
      red1[t] += red1[t + off];
    }
    __syncthreads();
  }
  if (t == 0) {
    outp[g * 2 + 0] = red0[0] / 127.f;
    outp[g * 2 + 1] = red1[0] / 127.f;
  }
}

// ---------------------------------------------------------------------------
extern "C" void kernel_launch(void* const* d_in, const int* in_sizes, int n_in,
                              void* d_out, int out_size, void* d_ws, size_t ws_size,
                              hipStream_t stream) {
  const float* x   = (const float*)d_in[0];
  const int* ei    = (const int*)d_in[1];
  const float* ew  = (const float*)d_in[2];
  // d_in[3] = batch: arange(N)//L -> pure reshape, unused
  const float* gw  = (const float*)d_in[4];
  const float* wih = (const float*)d_in[5];
  const float* whh = (const float*)d_in[6];
  const float* bih = (const float*)d_in[7];
  const float* bhh = (const float*)d_in[8];
  const float* w1  = (const float*)d_in[9];
  const float* b1  = (const float*)d_in[10];
  const float* w2  = (const float*)d_in[11];
  const float* b2  = (const float*)d_in[12];
  const float* wc1 = (const float*)d_in[13];
  const float* bc1 = (const float*)d_in[14];
  const float* wc2 = (const float*)d_in[15];
  const float* bc2 = (const float*)d_in[16];
  const float* bn1g = (const float*)d_in[17];
  const float* bn1b = (const float*)d_in[18];
  const float* bn2g = (const float*)d_in[19];
  const float* bn2b = (const float*)d_in[20];
  const float* myw = (const float*)d_in[21];
  const float* myb = (const float*)d_in[22];
  const float* mzw = (const float*)d_in[23];
  const float* mzb = (const float*)d_in[24];
  float* out = (float*)d_out;

  // ---------------- workspace layout ----------------
  // Persistent region (lives across GGNN + conv phases):
  float* ws = (float*)d_ws;
  unsigned short* PH = (unsigned short*)ws;       // 8,388,608 us (h planes, ping; final h)
  unsigned short* PL = PH + 8388608;
  unsigned short* xH = PL + 8388608;              // x planes
  unsigned short* xL = xH + 8388608;
  unsigned short* c1h  = xL + 8388608;            // conv weights bf16
  unsigned short* c1l  = c1h + 49152;
  unsigned short* cc1h = c1l + 49152;
  unsigned short* cc1l = cc1h + 196608;
  unsigned short* c2h  = cc1l + 196608;
  unsigned short* c2l  = c2h + 16384;
  unsigned short* cc2h = c2l + 16384;
  unsigned short* cc2l = cc2h + 65536;
  float* stats = (float*)(cc2l + 65536);          // 512 f
  float* Y2 = stats + 512;                        // 2,080,768 f ([g][127][128] f32)
  float* Z2 = Y2 + 2080768;                       // 4,161,536 f ([g][127][256] f32)
  float* shared0 = Z2 + 4161536;
  // GGNN-phase view of shared region:
  unsigned short* QH = (unsigned short*)shared0;  // h planes, pong
  unsigned short* QL = QH + 8388608;
  float* m = (float*)(QL + 8388608);              // 8,388,608 f (gemm out / gather in)
  unsigned short* aggH = (unsigned short*)(m + 8388608);
  unsigned short* aggL = aggH + 8388608;
  unsigned short* wihCh = aggL + 8388608;         // GRU weights bf16
  unsigned short* wihCl = wihCh + 49152;
  unsigned short* whhCh = wihCl + 49152;
  unsigned short* whhCl = whhCh + 49152;
  unsigned short* gwTh = whhCl + 49152;           // 98,304 us x2
  unsigned short* gwTl = gwTh + 98304;
  int* cnt    = (int*)(gwTl + 98304);             // 65,536
  int* rowptr = cnt + 65536;                      // 65,537
  int* cursor = rowptr + 65537;                   // 65,536
  int* col    = cursor + 65536;                   // 262,144
  float* wgt  = (float*)(col + 262144);           // 262,144
  float* ggnn_end = wgt + 262144;
  // Conv-phase view of shared region (aliases GGNN buffers, all dead by then):
  float* bufA = shared0;                          // 16,711,680 f (conv out, l-major)
  unsigned short* bufBH = (unsigned short*)(bufA + 16711680);  // pool1 planes
  unsigned short* bufBL = bufBH + 8323072;
  float* conv_end = (float*)(bufBL + 8323072);
  float* wend = (ggnn_end > conv_end) ? ggnn_end : conv_end;
  size_t needed = (size_t)(wend - ws) * 4;
  if (ws_size < needed) return;

  const int* src = ei;
  const int* dst = ei + EE;

  // one-time prep per launch
  k_prep<<<768, 256, 0, stream>>>(wih, whh, gw, w1, wc1, w2, wc2,
                                  wihCh, wihCl, whhCh, whhCl, gwTh, gwTl,
                                  c1h, c1l, cc1h, cc1l, c2h, c2l, cc2h, cc2l);
  k_castx<<<4096, 256, 0, stream>>>(x, xH, xL);
  hipMemsetAsync(cnt, 0, 65536 * 4, stream);
  k_hist<<<1024, 256, 0, stream>>>(dst, cnt);
  k_scan<<<1, 1024, 0, stream>>>(cnt, rowptr, cursor);
  k_fill<<<1024, 256, 0, stream>>>(src, dst, ew, cursor, col, wgt);

  // GGNN: 6 steps, ping-pong h planes. s=0 in: x planes; s=5 out: P planes.
  for (int s = 0; s < NSTEPS; s++) {
    const unsigned short* AH = (s == 0) ? xH : ((s & 1) ? QH : PH);
    const unsigned short* AL = (s == 0) ? xL : ((s & 1) ? QL : PL);
    unsigned short* OH = (s & 1) ? PH : QH;
    unsigned short* OL = (s & 1) ? PL : QL;
    k_gemm_mfma<<<1024, 256, 0, stream>>>(AH, AL, gwTh + s * 16384, gwTl + s * 16384, m);
    k_gather<<<8192, 256, 0, stream>>>(m, rowptr, col, wgt, aggH, aggL);
    k_gru_mfma<<<dim3(1024, 4), 256, 0, stream>>>(aggH, aggL, AH, AL, wihCh, wihCl,
                                                  whhCh, whhCl, bih, bhh, OH, OL);
  }

  // Y path: conv3 -> bufA [g][510][128]; pool -> bufB planes [g][254][128];
  //         1x1 -> bufA [g][254][128]; pool -> Y2 f32 [g][127][128]
  hipMemsetAsync(stats, 0, 512 * 4, stream);
  k_conv_mfma<128, 3, 128><<<dim3(8, 1, 128), 256, 0, stream>>>(
      PH, nullptr, PL, nullptr, c1h, c1l, b1, bufA, stats, 512, L1);
  k_bnpool<true><<<(GG * 128 * P1 + 255) / 256, 256, 0, stream>>>(
      bufA, nullptr, bufBH, bufBL, stats, bn1g, bn1b, 128, L1, P1, 3);
  hipMemsetAsync(stats, 0, 512 * 4, stream);
  k_conv_mfma<128, 1, 128><<<dim3(4, 1, 128), 256, 0, stream>>>(
      bufBH, nullptr, bufBL, nullptr, c2h, c2l, b2, bufA, stats, P1, P1);
  k_bnpool<false><<<(GG * 128 * P2 + 255) / 256, 256, 0, stream>>>(
      bufA, Y2, nullptr, nullptr, stats, bn1g, bn1b, 128, P1, P2, 2);

  // Z path: conv3(concat h,x) -> bufA [g][510][256]; pool -> bufB planes;
  //         1x1 -> bufA [g][254][256]; pool -> Z2 f32 [g][127][256]
  hipMemsetAsync(stats, 0, 512 * 4, stream);
  k_conv_mfma<256, 3, 128><<<dim3(8, 2, 128), 256, 0, stream>>>(
      PH, xH, PL, xL, cc1h, cc1l, bc1, bufA, stats, 512, L1);
  k_bnpool<true><<<(GG * 256 * P1 + 255) / 256, 256, 0, stream>>>(
      bufA, nullptr, bufBH, bufBL, stats, bn2g, bn2b, 256, L1, P1, 3);
  hipMemsetAsync(stats, 0, 512 * 4, stream);
  k_conv_mfma<256, 1, 256><<<dim3(4, 2, 128), 256, 0, stream>>>(
      bufBH, nullptr, bufBL, nullptr, cc2h, cc2l, bc2, bufA, stats, P1, P1);
  k_bnpool<false><<<(GG * 256 * P2 + 255) / 256, 256, 0, stream>>>(
      bufA, Z2, nullptr, nullptr, stats, bn2g, bn2b, 256, P1, P2, 2);

  // epilogue
  k_final<<<128, 128, 0, stream>>>(Y2, Z2, myw, myb, mzw, mzb, out);
}

// Round 6
// 2069.592 us; speedup vs baseline: 1.0455x; 1.0455x over previous
//
#include <hip/hip_runtime.h>
#include <math.h>

// Problem constants
#define NN 65536   // nodes
#define GG 128     // graphs
#define LL 512     // nodes per graph
#define DD 128     // feature dim
#define EE 262144  // edges
#define NSTEPS 6
#define CC 256     // concat dim
#define L1 510     // after k=3 valid conv
#define P1 254     // after pool(3,2)
#define P2 127     // after pool(2,2)

typedef __attribute__((ext_vector_type(8))) short s8bf;   // 8 bf16 in 4 VGPRs
typedef __attribute__((ext_vector_type(4))) float f4acc;  // MFMA accumulator

// fp32 -> bf16 (RNE) and back, as raw ushort
__device__ __forceinline__ unsigned short f2bf(float x) {
  unsigned u = __float_as_uint(x);
  unsigned r = u + 0x7FFFu + ((u >> 16) & 1u);
  return (unsigned short)(r >> 16);
}
__device__ __forceinline__ float bf2f(unsigned short h) {
  return __uint_as_float(((unsigned)h) << 16);
}
__device__ __forceinline__ unsigned short f2bf_sel(float x, int lo_sel) {
  unsigned short hi = f2bf(x);
  if (!lo_sel) return hi;
  return f2bf(x - bf2f(hi));
}
__device__ __forceinline__ uint2 pack4bf(float4 v, int lo_sel) {
  unsigned short s0 = f2bf_sel(v.x, lo_sel), s1 = f2bf_sel(v.y, lo_sel);
  unsigned short s2 = f2bf_sel(v.z, lo_sel), s3 = f2bf_sel(v.w, lo_sel);
  uint2 pk; pk.x = (unsigned)s0 | ((unsigned)s1 << 16);
  pk.y = (unsigned)s2 | ((unsigned)s3 << 16);
  return pk;
}

// ---------------------------------------------------------------------------
// prep: all weights to bf16 hi/lo in MFMA layouts.
// ---------------------------------------------------------------------------
__global__ __launch_bounds__(256) void k_prep(
    const float* __restrict__ wih, const float* __restrict__ whh,
    const float* __restrict__ gw,
    const float* __restrict__ w1, const float* __restrict__ wc1,
    const float* __restrict__ w2, const float* __restrict__ wc2,
    unsigned short* __restrict__ wihCh, unsigned short* __restrict__ wihCl,
    unsigned short* __restrict__ whhCh, unsigned short* __restrict__ whhCl,
    unsigned short* __restrict__ gwTh, unsigned short* __restrict__ gwTl,
    unsigned short* __restrict__ c1h, unsigned short* __restrict__ c1l,
    unsigned short* __restrict__ cc1h, unsigned short* __restrict__ cc1l,
    unsigned short* __restrict__ c2h, unsigned short* __restrict__ c2l,
    unsigned short* __restrict__ cc2h, unsigned short* __restrict__ cc2l) {
  int i = blockIdx.x * 256 + threadIdx.x;
  if (i < 49152) {  // GRU weights, elementwise hi/lo (already [384][128])
    float v = wih[i];
    unsigned short h_ = f2bf(v);
    wihCh[i] = h_; wihCl[i] = f2bf(v - bf2f(h_));
    float u = whh[i];
    unsigned short h2 = f2bf(u);
    whhCh[i] = h2; whhCl[i] = f2bf(u - bf2f(h2));
  }
  if (i < 98304) {  // gwT: i = s*16384 + col*128 + k
    int s = i >> 14; int r = i & 16383; int c = r >> 7; int k = r & 127;
    float v = gw[(s << 14) + k * 128 + c];
    unsigned short h_ = f2bf(v);
    gwTh[i] = h_; gwTl[i] = f2bf(v - bf2f(h_));
  }
  if (i < 49152) {  // c1: i = (tap*128+co)*128+ci ; src w1[co][ci][tap]
    int ci = i & 127; int r = i >> 7; int co = r & 127; int tap = r >> 7;
    float v = w1[(co * 128 + ci) * 3 + tap];
    unsigned short h_ = f2bf(v);
    c1h[i] = h_; c1l[i] = f2bf(v - bf2f(h_));
  }
  if (i < 196608) {  // cc1: i = (tap*256+co)*256+ci ; src wc1[co][ci][tap]
    int ci = i & 255; int r = i >> 8; int co = r & 255; int tap = r >> 8;
    float v = wc1[(co * 256 + ci) * 3 + tap];
    unsigned short h_ = f2bf(v);
    cc1h[i] = h_; cc1l[i] = f2bf(v - bf2f(h_));
  }
  if (i < 16384) {  // c2: identity layout [co][ci]
    float v = w2[i];
    unsigned short h_ = f2bf(v);
    c2h[i] = h_; c2l[i] = f2bf(v - bf2f(h_));
  }
  if (i < 65536) {  // cc2: identity layout [co][ci]
    float v = wc2[i];
    unsigned short h_ = f2bf(v);
    cc2h[i] = h_; cc2l[i] = f2bf(v - bf2f(h_));
  }
}

// ---------------------------------------------------------------------------
// x -> bf16 hi/lo planes (once per launch); 8 elems/thread, 16B stores.
// ---------------------------------------------------------------------------
__global__ __launch_bounds__(256) void k_castx(const float* __restrict__ x,
                                               unsigned short* __restrict__ xH,
                                               unsigned short* __restrict__ xL) {
  int i = blockIdx.x * 256 + threadIdx.x;  // 1,048,576 threads x 8 elems
  const float4* x4 = (const float4*)x;
  float4 a = x4[i * 2 + 0];
  float4 b = x4[i * 2 + 1];
  uint2 ha = pack4bf(a, 0), hb = pack4bf(b, 0);
  uint2 la = pack4bf(a, 1), lb = pack4bf(b, 1);
  uint4 hv; hv.x = ha.x; hv.y = ha.y; hv.z = hb.x; hv.w = hb.y;
  uint4 lv; lv.x = la.x; lv.y = la.y; lv.z = lb.x; lv.w = lb.y;
  *(uint4*)&xH[i * 8] = hv;
  *(uint4*)&xL[i * 8] = lv;
}

// ---------------------------------------------------------------------------
// CSR build (by dst) so the per-step aggregation is an atomic-free gather
// ---------------------------------------------------------------------------
__global__ __launch_bounds__(256) void k_hist(const int* __restrict__ dst, int* __restrict__ cnt) {
  int e = blockIdx.x * 256 + threadIdx.x;
  if (e < EE) atomicAdd(&cnt[dst[e]], 1);
}

__global__ __launch_bounds__(1024) void k_scan(const int* __restrict__ cnt,
                                               int* __restrict__ rowptr,
                                               int* __restrict__ cursor) {
  __shared__ int part[1024];
  int t = threadIdx.x;
  int base = t * 64;
  int s = 0;
  for (int i = 0; i < 64; i++) s += cnt[base + i];
  part[t] = s;
  __syncthreads();
  for (int off = 1; off < 1024; off <<= 1) {
    int v = part[t];
    int u = (t >= off) ? part[t - off] : 0;
    __syncthreads();
    part[t] = v + u;
    __syncthreads();
  }
  int run = part[t] - s;  // exclusive prefix of this chunk
  for (int i = 0; i < 64; i++) {
    rowptr[base + i] = run;
    cursor[base + i] = run;
    run += cnt[base + i];
  }
  if (t == 1023) rowptr[NN] = run;
}

__global__ __launch_bounds__(256) void k_fill(const int* __restrict__ src,
                                              const int* __restrict__ dst,
                                              const float* __restrict__ ew,
                                              int* __restrict__ cursor,
                                              int* __restrict__ col,
                                              float* __restrict__ wgt) {
  int e = blockIdx.x * 256 + threadIdx.x;
  if (e < EE) {
    int d = dst[e];
    int p = atomicAdd(&cursor[d], 1);
    col[p] = src[e];
    wgt[p] = ew[e];
  }
}

// ---------------------------------------------------------------------------
// m = h @ W via split-bf16 MFMA; A pre-split bf16 hi/lo planes, staged as
// pure 16B copies. Pass order: hh, hl, lh. R1 grid/LDS/global patterns;
// waves re-tiled 2x2: wave = 32 rows (wr, MT=2) x 64 cols (wc, NT=4)
// -> 2 LDS A-reads feed 8 MFMAs (256 B/MFMA, was 512).
// ---------------------------------------------------------------------------
__global__ __launch_bounds__(256, 4) void k_gemm_mfma(
    const unsigned short* __restrict__ Ah, const unsigned short* __restrict__ Al,
    const unsigned short* __restrict__ Wh, const unsigned short* __restrict__ Wl,
    float* __restrict__ Cout) {
  __shared__ __attribute__((aligned(16))) unsigned short As[64 * 136];
  int t = threadIdx.x;
  int r0 = blockIdx.x * 64;
  int wv = t >> 6, lane = t & 63;
  int ln = lane & 15, q = lane >> 4;
  int wr = wv & 1, wc = wv >> 1;
  f4acc acc[2][4];
#pragma unroll
  for (int mt = 0; mt < 2; mt++)
#pragma unroll
    for (int nt = 0; nt < 4; nt++) acc[mt][nt] = (f4acc)0.f;

  for (int p = 0; p < 3; p++) {
    if (p != 1) {  // stage A full K (hi at p0, lo at p2): 4 exact 16B copies/thread
      const unsigned short* S = (p == 2) ? Al : Ah;
      if (p) __syncthreads();
#pragma unroll
      for (int it = 0; it < 4; it++) {
        int v8 = it * 256 + t;
        int row = v8 >> 4, k = (v8 & 15) * 8;
        *(uint4*)&As[row * 136 + k] = *(const uint4*)&S[(r0 + row) * 128 + k];
      }
      __syncthreads();
    }
    const unsigned short* W = (p == 1) ? Wl : Wh;
#pragma unroll
    for (int k0 = 0; k0 < 128; k0 += 32) {
      s8bf af[2], bf[4];
#pragma unroll
      for (int nt = 0; nt < 4; nt++)
        bf[nt] = *(const s8bf*)&W[(wc * 64 + nt * 16 + ln) * 128 + k0 + q * 8];
#pragma unroll
      for (int mt = 0; mt < 2; mt++)
        af[mt] = *(const s8bf*)&As[(wr * 32 + mt * 16 + ln) * 136 + k0 + q * 8];
#pragma unroll
      for (int mt = 0; mt < 2; mt++)
#pragma unroll
        for (int nt = 0; nt < 4; nt++)
          acc[mt][nt] = __builtin_amdgcn_mfma_f32_16x16x32_bf16(af[mt], bf[nt], acc[mt][nt], 0, 0, 0);
    }
  }
#pragma unroll
  for (int mt = 0; mt < 2; mt++)
#pragma unroll
    for (int nt = 0; nt < 4; nt++)
#pragma unroll
      for (int reg = 0; reg < 4; reg++) {
        int r = r0 + wr * 32 + mt * 16 + q * 4 + reg;
        Cout[r * 128 + wc * 64 + nt * 16 + ln] = acc[mt][nt][reg];
      }
}

// ---------------------------------------------------------------------------
// agg[n,:] = sum over in-edges of m[src,:]*w.  Emits agg directly as bf16
// hi/lo planes. (R1-exact.)
// ---------------------------------------------------------------------------
__global__ __launch_bounds__(256) void k_gather(const float* __restrict__ m,
                                                const int* __restrict__ rowptr,
                                                const int* __restrict__ col,
                                                const float* __restrict__ wgt,
                                                unsigned short* __restrict__ aggH,
                                                unsigned short* __restrict__ aggL) {
  int t = threadIdx.x;
  int n = blockIdx.x * 8 + (t >> 5);
  int c4 = t & 31;
  const float4* m4 = (const float4*)m;
  int s0 = rowptr[n], s1 = rowptr[n + 1];
  float ax = 0.f, ay = 0.f, az = 0.f, aw = 0.f;
  int e = s0;
  for (; e + 2 <= s1; e += 2) {
    int cA = col[e], cB = col[e + 1];
    float wA = wgt[e], wB = wgt[e + 1];
    float4 vA = m4[cA * 32 + c4];
    float4 vB = m4[cB * 32 + c4];
    ax += vA.x * wA + vB.x * wB;
    ay += vA.y * wA + vB.y * wB;
    az += vA.z * wA + vB.z * wB;
    aw += vA.w * wA + vB.w * wB;
  }
  if (e < s1) {
    int cA = col[e];
    float wA = wgt[e];
    float4 vA = m4[cA * 32 + c4];
    ax += vA.x * wA; ay += vA.y * wA; az += vA.z * wA; aw += vA.w * wA;
  }
  unsigned short h0 = f2bf(ax), h1 = f2bf(ay), h2 = f2bf(az), h3 = f2bf(aw);
  unsigned short l0 = f2bf(ax - bf2f(h0)), l1 = f2bf(ay - bf2f(h1));
  unsigned short l2 = f2bf(az - bf2f(h2)), l3 = f2bf(aw - bf2f(h3));
  uint2 hpk, lpk;
  hpk.x = (unsigned)h0 | ((unsigned)h1 << 16); hpk.y = (unsigned)h2 | ((unsigned)h3 << 16);
  lpk.x = (unsigned)l0 | ((unsigned)l1 << 16); lpk.y = (unsigned)l2 | ((unsigned)l3 << 16);
  int base = n * 128 + c4 * 4;
  *(uint2*)&aggH[base] = hpk;
  *(uint2*)&aggL[base] = lpk;
}

// ---------------------------------------------------------------------------
// Fused dual GEMM + GRU via split-bf16 MFMA; both A matrices as bf16 hi/lo
// planes. R1 grid (1024,2) / LDS / staging; waves re-tiled 2x2: wave =
// 32 rows (wr) x 32 d (wc, NT=2 per gate) -> 4 LDS A-reads feed 24 MFMAs
// (170 B/MFMA, was 341). Output bf16 hi/lo planes; hold = hi+lo. NOT in-place.
// ---------------------------------------------------------------------------
__global__ __launch_bounds__(256, 2) void k_gru_mfma(
    const unsigned short* __restrict__ aggH, const unsigned short* __restrict__ aggL,
    const unsigned short* __restrict__ hinH, const unsigned short* __restrict__ hinL,
    const unsigned short* __restrict__ wihCh, const unsigned short* __restrict__ wihCl,
    const unsigned short* __restrict__ whhCh, const unsigned short* __restrict__ whhCl,
    const float* __restrict__ bih, const float* __restrict__ bhh,
    unsigned short* __restrict__ houtH, unsigned short* __restrict__ houtL) {
  __shared__ __attribute__((aligned(16))) unsigned short As[2 * 64 * 136];  // [mat][row][k]
  int t = threadIdx.x;
  int r0 = blockIdx.x * 64;
  int d0 = blockIdx.y * 64;
  int wv = t >> 6, lane = t & 63;
  int ln = lane & 15, q = lane >> 4;
  int wr = wv & 1, wc = wv >> 1;
  f4acc acc[2][6][2];
#pragma unroll
  for (int mt = 0; mt < 2; mt++)
#pragma unroll
    for (int tg = 0; tg < 6; tg++)
#pragma unroll
      for (int nt = 0; nt < 2; nt++) acc[mt][tg][nt] = (f4acc)0.f;

  for (int p = 0; p < 3; p++) {
    if (p != 1) {  // stage both A mats full K: hi at p0, lo at p2
      const unsigned short* s0 = (p == 2) ? aggL : aggH;
      const unsigned short* s1 = (p == 2) ? hinL : hinH;
      if (p) __syncthreads();
#pragma unroll
      for (int it = 0; it < 8; it++) {
        int v8 = it * 256 + t;          // 0..2047
        int mat = v8 >> 10;
        int row = (v8 >> 4) & 63, k = (v8 & 15) * 8;
        const unsigned short* S = mat ? s1 : s0;
        *(uint4*)&As[mat * 8704 + row * 136 + k] = *(const uint4*)&S[(r0 + row) * 128 + k];
      }
      __syncthreads();
    }
    const unsigned short* wx = (p == 1) ? wihCl : wihCh;
    const unsigned short* wh = (p == 1) ? whhCl : whhCh;
#pragma unroll
    for (int k0 = 0; k0 < 128; k0 += 32) {
      s8bf af[2][2], bfr[6][2];
#pragma unroll
      for (int tg = 0; tg < 6; tg++) {
        int gate = (tg < 3) ? tg : tg - 3;
        const unsigned short* W = (tg < 3) ? wx : wh;
#pragma unroll
        for (int nt = 0; nt < 2; nt++)
          bfr[tg][nt] = *(const s8bf*)&W[(gate * 128 + d0 + wc * 32 + nt * 16 + ln) * 128 + k0 + q * 8];
      }
#pragma unroll
      for (int mat = 0; mat < 2; mat++)
#pragma unroll
        for (int mt = 0; mt < 2; mt++)
          af[mat][mt] = *(const s8bf*)&As[mat * 8704 + (wr * 32 + mt * 16 + ln) * 136 + k0 + q * 8];
#pragma unroll
      for (int mt = 0; mt < 2; mt++)
#pragma unroll
        for (int tg = 0; tg < 6; tg++)
#pragma unroll
          for (int nt = 0; nt < 2; nt++)
            acc[mt][tg][nt] = __builtin_amdgcn_mfma_f32_16x16x32_bf16(
                af[tg < 3 ? 0 : 1][mt], bfr[tg][nt], acc[mt][tg][nt], 0, 0, 0);
    }
  }
#pragma unroll
  for (int nt = 0; nt < 2; nt++) {
    int d = d0 + wc * 32 + nt * 16 + ln;
    float bi0 = bih[d], bi1 = bih[128 + d], bi2 = bih[256 + d];
    float bh0 = bhh[d], bh1 = bhh[128 + d], bh2 = bhh[256 + d];
#pragma unroll
    for (int mt = 0; mt < 2; mt++) {
#pragma unroll
      for (int reg = 0; reg < 4; reg++) {
        int r = r0 + wr * 32 + mt * 16 + q * 4 + reg;
        int idx = r * 128 + d;
        float hold = bf2f(hinH[idx]) + bf2f(hinL[idx]);
        float xr = acc[mt][0][nt][reg] + bi0;
        float xz = acc[mt][1][nt][reg] + bi1;
        float xn = acc[mt][2][nt][reg] + bi2;
        float hr = acc[mt][3][nt][reg] + bh0;
        float hz = acc[mt][4][nt][reg] + bh1;
        float hn = acc[mt][5][nt][reg] + bh2;
        float rr = 1.f / (1.f + expf(-(xr + hr)));
        float zz = 1.f / (1.f + expf(-(xz + hz)));
        float nnv = tanhf(xn + rr * hn);
        float hv = (1.f - zz) * nnv + zz * hold;
        unsigned short hh = f2bf(hv);
        houtH[idx] = hh;
        houtL[idx] = f2bf(hv - bf2f(hh));
      }
    }
  }
}

// ---------------------------------------------------------------------------
// Generic implicit-GEMM conv via split-bf16 MFMA. R1 grid/LDS/staging/global
// patterns; waves re-tiled 2x2: wave = 32 l-rows (wr) x 64 co (wc, NT=4)
// -> 2 LDS A-reads feed 8 MFMAs (256 B/MFMA, was 512). B direct-from-global
// with 1-deep prefetch. Stats epilogue: q-shuffle pre-reduce, then atomics.
// Block: 64 l-rows x 128 co; grid (ceil(Lco/64), CIN/128, G).
// ---------------------------------------------------------------------------
template<int CIN, int TAPS, int WA>
__global__ __launch_bounds__(256, 4) void k_conv_mfma(
    const unsigned short* __restrict__ hiA, const unsigned short* __restrict__ hiB,
    const unsigned short* __restrict__ loA, const unsigned short* __restrict__ loB,
    const unsigned short* __restrict__ Wh, const unsigned short* __restrict__ Wl,
    const float* __restrict__ bias, float* __restrict__ out,
    float* __restrict__ stats, int Lin, int Lco) {
  constexpr int APAD = CIN + 8;
  constexpr int ROWS = 64 + TAPS - 1;
  constexpr int NCH = CIN / 32;
  constexpr int TOT8 = ROWS * CIN / 8;       // 16B chunks to stage
  constexpr int NIT = (TOT8 + 255) / 256;
  constexpr int NINNER = TAPS * NCH;
  __shared__ __attribute__((aligned(16))) unsigned short As[ROWS * APAD];
  __shared__ float sred[256];
  const int g = blockIdx.z, co0 = blockIdx.y * 128, l0 = blockIdx.x * 64;
  const int t = threadIdx.x;
  const int wv = t >> 6, lane = t & 63, ln = lane & 15, q = lane >> 4;
  const int wr = wv & 1, wc = wv >> 1;
  f4acc acc[2][4];
#pragma unroll
  for (int mt = 0; mt < 2; mt++)
#pragma unroll
    for (int nt = 0; nt < 4; nt++) acc[mt][nt] = (f4acc)0.f;

  // pass order: (Ah,Bh), (Ah,Bl), (Al,Bh)
  for (int p = 0; p < 3; p++) {
    if (p != 1) {
      const unsigned short* pA = (p == 2) ? loA : hiA;
      const unsigned short* pB = (p == 2) ? loB : hiB;
      if (p) __syncthreads();
#pragma unroll
      for (int it = 0; it < NIT; it++) {
        int v8 = it * 256 + t;
        if (NIT * 256 == TOT8 || v8 < TOT8) {
          int row = (v8 * 8) / CIN, ch = (v8 * 8) % CIN;
          int lr = l0 + row; if (lr > Lin - 1) lr = Lin - 1;
          uint4 v;
          if (ch < WA) v = *(const uint4*)&pA[(g * Lin + lr) * WA + ch];
          else         v = *(const uint4*)&pB[(g * Lin + lr) * WA + ch - WA];
          *(uint4*)&As[row * APAD + ch] = v;
        }
      }
      __syncthreads();
    }
    const unsigned short* W = (p == 1) ? Wl : Wh;
    // flat (tap, ch) loop with 1-deep B prefetch
    s8bf bcur[4], bnxt[4];
#pragma unroll
    for (int nt = 0; nt < 4; nt++)
      bcur[nt] = *(const s8bf*)&W[(co0 + wc * 64 + nt * 16 + ln) * CIN + q * 8];
#pragma unroll
    for (int it = 0; it < NINNER; it++) {
      const int tap = it / NCH, ch = it % NCH;
      if (it + 1 < NINNER) {
        const int ntap = (it + 1) / NCH, nch = (it + 1) % NCH;
#pragma unroll
        for (int nt = 0; nt < 4; nt++)
          bnxt[nt] = *(const s8bf*)&W[(ntap * CIN + co0 + wc * 64 + nt * 16 + ln) * CIN + nch * 32 + q * 8];
      }
      const int c0 = ch * 32;
      s8bf af[2];
#pragma unroll
      for (int mt = 0; mt < 2; mt++)
        af[mt] = *(const s8bf*)&As[(wr * 32 + mt * 16 + ln + tap) * APAD + c0 + q * 8];
#pragma unroll
      for (int mt = 0; mt < 2; mt++)
#pragma unroll
        for (int nt = 0; nt < 4; nt++)
          acc[mt][nt] = __builtin_amdgcn_mfma_f32_16x16x32_bf16(af[mt], bcur[nt], acc[mt][nt], 0, 0, 0);
      if (it + 1 < NINNER) {
#pragma unroll
        for (int nt = 0; nt < 4; nt++) bcur[nt] = bnxt[nt];
      }
    }
  }
  // epilogue: bias, store [g][l][co], per-co sum/sumsq (q-shuffle pre-reduce)
  sred[t] = 0.f;
  __syncthreads();
#pragma unroll
  for (int nt = 0; nt < 4; nt++) {
    int cl = wc * 64 + nt * 16 + ln;
    int co = co0 + cl;
    float bv = bias[co];
    float s = 0.f, s2 = 0.f;
#pragma unroll
    for (int mt = 0; mt < 2; mt++)
#pragma unroll
      for (int reg = 0; reg < 4; reg++) {
        int l = l0 + wr * 32 + mt * 16 + q * 4 + reg;
        if (l < Lco) {
          float v = acc[mt][nt][reg] + bv;
          out[(g * Lco + l) * CIN + co] = v;
          s += v; s2 += v * v;
        }
      }
    // reduce over q (lanes differ by 16, 32 within the 64-lane wave)
    s += __shfl_xor(s, 16);  s += __shfl_xor(s, 32);
    s2 += __shfl_xor(s2, 16); s2 += __shfl_xor(s2, 32);
    if (q == 0) {
      atomicAdd(&sred[cl], s);
      atomicAdd(&sred[128 + cl], s2);
    }
  }
  __syncthreads();
  if (t < 128) atomicAdd(&stats[co0 + t], sred[t]);
  else atomicAdd(&stats[CIN + co0 + (t - 128)], sred[t]);
}

// ---------------------------------------------------------------------------
// BN(training stats) -> ReLU -> maxpool(pk, stride 2); l-major both sides.
// PLANES=true: emit bf16 hi/lo planes (for 1x1 conv input);
// PLANES=false: emit f32 (for k_final).
// ---------------------------------------------------------------------------
template<bool PLANES>
__global__ __launch_bounds__(256) void k_bnpool(const float* __restrict__ in,
                                                float* __restrict__ outF,
                                                unsigned short* __restrict__ outH,
                                                unsigned short* __restrict__ outL,
                                                const float* __restrict__ stats,
                                                const float* __restrict__ gamma,
                                                const float* __restrict__ beta,
                                                int Cch, int LinC, int Lout, int pk) {
  int idx = blockIdx.x * 256 + threadIdx.x;
  int total = GG * Cch * Lout;
  if (idx >= total) return;
  int c = idx & (Cch - 1);
  int r = idx / Cch;
  int p = r % Lout;
  int g = r / Lout;
  float cntf = (float)(GG * LinC);
  float mean = stats[c] / cntf;
  float var = stats[Cch + c] / cntf - mean * mean;
  float inv = rsqrtf(var + 1e-5f) * gamma[c];
  float sh = beta[c] - mean * inv;
  const float* base = &in[((g * LinC) + 2 * p) * Cch + c];
  float m = 0.f;  // relu output >= 0
  for (int k = 0; k < pk; k++) {
    float v = fmaxf(base[k * Cch] * inv + sh, 0.f);
    m = fmaxf(m, v);
  }
  int o = (g * Lout + p) * Cch + c;
  if (PLANES) {
    unsigned short hh = f2bf(m);
    outH[o] = hh;
    outL[o] = f2bf(m - bf2f(hh));
  } else {
    outF[o] = m;
  }
}

// ---------------------------------------------------------------------------
// final: Y2 [g][127][128], Z2 [g][127][256] l-major f32
// ---------------------------------------------------------------------------
__global__ __launch_bounds__(128) void k_final(const float* __restrict__ Y2,
                                               const float* __restrict__ Z2,
                                               const float* __restrict__ myw,
                                               const float* __restrict__ myb,
                                               const float* __restrict__ mzw,
                                               const float* __restrict__ mzb,
                                               float* __restrict__ outp) {
  __shared__ float red0[128];
  __shared__ float red1[128];
  int g = blockIdx.x;
  int t = threadIdx.x;
  float y0 = myb[0], y1 = myb[1], z0 = mzb[0], z1 = mzb[1];
  if (t < P2) {
    const float* yb = &Y2[(g * P2 + t) * 128];
    for (int c = 0; c < 128; c++) {
      float v = yb[c];
      y0 += v * myw[c];
      y1 += v * myw[128 + c];
    }
    const float* zb = &Z2[(g * P2 + t) * 256];
    for (int c = 0; c < 256; c++) {
      float v = zb[c];
      z0 += v * mzw[c];
      z1 += v * mzw[256 + c];
    }
  }
  red0[t] = (t < P2) ? y0 * z0 : 0.f;
  red1[t] = (t < P2) ? y1 * z1 : 0.f;
  __syncthreads();
  for (int off = 64; off > 0; off >>= 1) {
    if (t < off) {
      red0[t] += red0[t + off];
      red1[t] += red1[t + off];
    }
    __syncthreads();
  }
  if (t == 0) {
    outp[g * 2 + 0] = red0[0] / 127.f;
    outp[g * 2 + 1] = red1[0] / 127.f;
  }
}

// ---------------------------------------------------------------------------
extern "C" void kernel_launch(void* const* d_in, const int* in_sizes, int n_in,
                              void* d_out, int out_size, void* d_ws, size_t ws_size,
                              hipStream_t stream) {
  const float* x   = (const float*)d_in[0];
  const int* ei    = (const int*)d_in[1];
  const float* ew  = (const float*)d_in[2];
  // d_in[3] = batch: arange(N)//L -> pure reshape, unused
  const float* gw  = (const float*)d_in[4];
  const float* wih = (const float*)d_in[5];
  const float* whh = (const float*)d_in[6];
  const float* bih = (const float*)d_in[7];
  const float* bhh = (const float*)d_in[8];
  const float* w1  = (const float*)d_in[9];
  const float* b1  = (const float*)d_in[10];
  const float* w2  = (const float*)d_in[11];
  const float* b2  = (const float*)d_in[12];
  const float* wc1 = (const float*)d_in[13];
  const float* bc1 = (const float*)d_in[14];
  const float* wc2 = (const float*)d_in[15];
  const float* bc2 = (const float*)d_in[16];
  const float* bn1g = (const float*)d_in[17];
  const float* bn1b = (const float*)d_in[18];
  const float* bn2g = (const float*)d_in[19];
  const float* bn2b = (const float*)d_in[20];
  const float* myw = (const float*)d_in[21];
  const float* myb = (const float*)d_in[22];
  const float* mzw = (const float*)d_in[23];
  const float* mzb = (const float*)d_in[24];
  float* out = (float*)d_out;

  // ---------------- workspace layout ----------------
  // Persistent region (lives across GGNN + conv phases):
  float* ws = (float*)d_ws;
  unsigned short* PH = (unsigned short*)ws;       // 8,388,608 us (h planes, ping; final h)
  unsigned short* PL = PH + 8388608;
  unsigned short* xH = PL + 8388608;              // x planes
  unsigned short* xL = xH + 8388608;
  unsigned short* c1h  = xL + 8388608;            // conv weights bf16
  unsigned short* c1l  = c1h + 49152;
  unsigned short* cc1h = c1l + 49152;
  unsigned short* cc1l = cc1h + 196608;
  unsigned short* c2h  = cc1l + 196608;
  unsigned short* c2l  = c2h + 16384;
  unsigned short* cc2h = c2l + 16384;
  unsigned short* cc2l = cc2h + 65536;
  float* stats = (float*)(cc2l + 65536);          // 512 f
  float* Y2 = stats + 512;                        // 2,080,768 f ([g][127][128] f32)
  float* Z2 = Y2 + 2080768;                       // 4,161,536 f ([g][127][256] f32)
  float* shared0 = Z2 + 4161536;
  // GGNN-phase view of shared region:
  unsigned short* QH = (unsigned short*)shared0;  // h planes, pong
  unsigned short* QL = QH + 8388608;
  float* m = (float*)(QL + 8388608);              // 8,388,608 f (gemm out / gather in)
  unsigned short* aggH = (unsigned short*)(m + 8388608);
  unsigned short* aggL = aggH + 8388608;
  unsigned short* wihCh = aggL + 8388608;         // GRU weights bf16
  unsigned short* wihCl = wihCh + 49152;
  unsigned short* whhCh = wihCl + 49152;
  unsigned short* whhCl = whhCh + 49152;
  unsigned short* gwTh = whhCl + 49152;           // 98,304 us x2
  unsigned short* gwTl = gwTh + 98304;
  int* cnt    = (int*)(gwTl + 98304);             // 65,536
  int* rowptr = cnt + 65536;                      // 65,537
  int* cursor = rowptr + 65537;                   // 65,536
  int* col    = cursor + 65536;                   // 262,144
  float* wgt  = (float*)(col + 262144);           // 262,144
  float* ggnn_end = wgt + 262144;
  // Conv-phase view of shared region (aliases GGNN buffers, all dead by then):
  float* bufA = shared0;                          // 16,711,680 f (conv out, l-major)
  unsigned short* bufBH = (unsigned short*)(bufA + 16711680);  // pool1 planes
  unsigned short* bufBL = bufBH + 8323072;
  float* conv_end = (float*)(bufBL + 8323072);
  float* wend = (ggnn_end > conv_end) ? ggnn_end : conv_end;
  size_t needed = (size_t)(wend - ws) * 4;
  if (ws_size < needed) return;

  const int* src = ei;
  const int* dst = ei + EE;

  // one-time prep per launch
  k_prep<<<768, 256, 0, stream>>>(wih, whh, gw, w1, wc1, w2, wc2,
                                  wihCh, wihCl, whhCh, whhCl, gwTh, gwTl,
                                  c1h, c1l, cc1h, cc1l, c2h, c2l, cc2h, cc2l);
  k_castx<<<4096, 256, 0, stream>>>(x, xH, xL);
  hipMemsetAsync(cnt, 0, 65536 * 4, stream);
  k_hist<<<1024, 256, 0, stream>>>(dst, cnt);
  k_scan<<<1, 1024, 0, stream>>>(cnt, rowptr, cursor);
  k_fill<<<1024, 256, 0, stream>>>(src, dst, ew, cursor, col, wgt);

  // GGNN: 6 steps, ping-pong h planes. s=0 in: x planes; s=5 out: P planes.
  for (int s = 0; s < NSTEPS; s++) {
    const unsigned short* AH = (s == 0) ? xH : ((s & 1) ? QH : PH);
    const unsigned short* AL = (s == 0) ? xL : ((s & 1) ? QL : PL);
    unsigned short* OH = (s & 1) ? PH : QH;
    unsigned short* OL = (s & 1) ? PL : QL;
    k_gemm_mfma<<<1024, 256, 0, stream>>>(AH, AL, gwTh + s * 16384, gwTl + s * 16384, m);
    k_gather<<<8192, 256, 0, stream>>>(m, rowptr, col, wgt, aggH, aggL);
    k_gru_mfma<<<dim3(1024, 2), 256, 0, stream>>>(aggH, aggL, AH, AL, wihCh, wihCl,
                                                  whhCh, whhCl, bih, bhh, OH, OL);
  }

  // Y path: conv3 -> bufA [g][510][128]; pool -> bufB planes [g][254][128];
  //         1x1 -> bufA [g][254][128]; pool -> Y2 f32 [g][127][128]
  hipMemsetAsync(stats, 0, 512 * 4, stream);
  k_conv_mfma<128, 3, 128><<<dim3(8, 1, 128), 256, 0, stream>>>(
      PH, nullptr, PL, nullptr, c1h, c1l, b1, bufA, stats, 512, L1);
  k_bnpool<true><<<(GG * 128 * P1 + 255) / 256, 256, 0, stream>>>(
      bufA, nullptr, bufBH, bufBL, stats, bn1g, bn1b, 128, L1, P1, 3);
  hipMemsetAsync(stats, 0, 512 * 4, stream);
  k_conv_mfma<128, 1, 128><<<dim3(4, 1, 128), 256, 0, stream>>>(
      bufBH, nullptr, bufBL, nullptr, c2h, c2l, b2, bufA, stats, P1, P1);
  k_bnpool<false><<<(GG * 128 * P2 + 255) / 256, 256, 0, stream>>>(
      bufA, Y2, nullptr, nullptr, stats, bn1g, bn1b, 128, P1, P2, 2);

  // Z path: conv3(concat h,x) -> bufA [g][510][256]; pool -> bufB planes;
  //         1x1 -> bufA [g][254][256]; pool -> Z2 f32 [g][127][256]
  hipMemsetAsync(stats, 0, 512 * 4, stream);
  k_conv_mfma<256, 3, 128><<<dim3(8, 2, 128), 256, 0, stream>>>(
      PH, xH, PL, xL, cc1h, cc1l, bc1, bufA, stats, 512, L1);
  k_bnpool<true><<<(GG * 256 * P1 + 255) / 256, 256, 0, stream>>>(
      bufA, nullptr, bufBH, bufBL, stats, bn2g, bn2b, 256, L1, P1, 3);
  hipMemsetAsync(stats, 0, 512 * 4, stream);
  k_conv_mfma<256, 1, 256><<<dim3(4, 2, 128), 256, 0, stream>>>(
      bufBH, nullptr, bufBL, nullptr, cc2h, cc2l, bc2, bufA, stats, P1, P1);
  k_bnpool<false><<<(GG * 256 * P2 + 255) / 256, 256, 0, stream>>>(
      bufA, Z2, nullptr, nullptr, stats, bn2g, bn2b, 256, P1, P2, 2);

  // epilogue
  k_final<<<128, 128, 0, stream>>>(Y2, Z2, myw, myb, mzw, mzb, out);
}

// Round 7
// 1633.968 us; speedup vs baseline: 1.3243x; 1.2666x over previous
//
#include <hip/hip_runtime.h>
#include <math.h>

// Problem constants
#define NN 65536   // nodes
#define GG 128     // graphs
#define LL 512     // nodes per graph
#define DD 128     // feature dim
#define EE 262144  // edges
#define NSTEPS 6
#define CC 256     // concat dim
#define L1 510     // after k=3 valid conv
#define P1 254     // after pool(3,2)
#define P2 127     // after pool(2,2)

typedef __attribute__((ext_vector_type(8))) short s8bf;   // 8 bf16 in 4 VGPRs
typedef __attribute__((ext_vector_type(4))) float f4acc;  // MFMA accumulator

// fp32 -> bf16 (RNE) and back, as raw ushort
__device__ __forceinline__ unsigned short f2bf(float x) {
  unsigned u = __float_as_uint(x);
  unsigned r = u + 0x7FFFu + ((u >> 16) & 1u);
  return (unsigned short)(r >> 16);
}
__device__ __forceinline__ float bf2f(unsigned short h) {
  return __uint_as_float(((unsigned)h) << 16);
}
__device__ __forceinline__ unsigned short f2bf_sel(float x, int lo_sel) {
  unsigned short hi = f2bf(x);
  if (!lo_sel) return hi;
  return f2bf(x - bf2f(hi));
}
__device__ __forceinline__ uint2 pack4bf(float4 v, int lo_sel) {
  unsigned short s0 = f2bf_sel(v.x, lo_sel), s1 = f2bf_sel(v.y, lo_sel);
  unsigned short s2 = f2bf_sel(v.z, lo_sel), s3 = f2bf_sel(v.w, lo_sel);
  uint2 pk; pk.x = (unsigned)s0 | ((unsigned)s1 << 16);
  pk.y = (unsigned)s2 | ((unsigned)s3 << 16);
  return pk;
}

// async 16B global -> LDS (wave-uniform LDS base + lane*16; our per-lane ptr
// satisfies that by construction). Drained by __syncthreads()'s vmcnt(0).
__device__ __forceinline__ void gload_lds16(const unsigned short* g, unsigned short* l) {
  __builtin_amdgcn_global_load_lds(
      (const __attribute__((address_space(1))) unsigned int*)g,
      (__attribute__((address_space(3))) unsigned int*)l, 16, 0, 0);
}

// ---------------------------------------------------------------------------
// prep: all weights to bf16 hi/lo in MFMA layouts.
// ---------------------------------------------------------------------------
__global__ __launch_bounds__(256) void k_prep(
    const float* __restrict__ wih, const float* __restrict__ whh,
    const float* __restrict__ gw,
    const float* __restrict__ w1, const float* __restrict__ wc1,
    const float* __restrict__ w2, const float* __restrict__ wc2,
    unsigned short* __restrict__ wihCh, unsigned short* __restrict__ wihCl,
    unsigned short* __restrict__ whhCh, unsigned short* __restrict__ whhCl,
    unsigned short* __restrict__ gwTh, unsigned short* __restrict__ gwTl,
    unsigned short* __restrict__ c1h, unsigned short* __restrict__ c1l,
    unsigned short* __restrict__ cc1h, unsigned short* __restrict__ cc1l,
    unsigned short* __restrict__ c2h, unsigned short* __restrict__ c2l,
    unsigned short* __restrict__ cc2h, unsigned short* __restrict__ cc2l) {
  int i = blockIdx.x * 256 + threadIdx.x;
  if (i < 49152) {  // GRU weights, elementwise hi/lo (already [384][128])
    float v = wih[i];
    unsigned short h_ = f2bf(v);
    wihCh[i] = h_; wihCl[i] = f2bf(v - bf2f(h_));
    float u = whh[i];
    unsigned short h2 = f2bf(u);
    whhCh[i] = h2; whhCl[i] = f2bf(u - bf2f(h2));
  }
  if (i < 98304) {  // gwT: i = s*16384 + col*128 + k
    int s = i >> 14; int r = i & 16383; int c = r >> 7; int k = r & 127;
    float v = gw[(s << 14) + k * 128 + c];
    unsigned short h_ = f2bf(v);
    gwTh[i] = h_; gwTl[i] = f2bf(v - bf2f(h_));
  }
  if (i < 49152) {  // c1: i = (tap*128+co)*128+ci ; src w1[co][ci][tap]
    int ci = i & 127; int r = i >> 7; int co = r & 127; int tap = r >> 7;
    float v = w1[(co * 128 + ci) * 3 + tap];
    unsigned short h_ = f2bf(v);
    c1h[i] = h_; c1l[i] = f2bf(v - bf2f(h_));
  }
  if (i < 196608) {  // cc1: i = (tap*256+co)*256+ci ; src wc1[co][ci][tap]
    int ci = i & 255; int r = i >> 8; int co = r & 255; int tap = r >> 8;
    float v = wc1[(co * 256 + ci) * 3 + tap];
    unsigned short h_ = f2bf(v);
    cc1h[i] = h_; cc1l[i] = f2bf(v - bf2f(h_));
  }
  if (i < 16384) {  // c2: identity layout [co][ci]
    float v = w2[i];
    unsigned short h_ = f2bf(v);
    c2h[i] = h_; c2l[i] = f2bf(v - bf2f(h_));
  }
  if (i < 65536) {  // cc2: identity layout [co][ci]
    float v = wc2[i];
    unsigned short h_ = f2bf(v);
    cc2h[i] = h_; cc2l[i] = f2bf(v - bf2f(h_));
  }
}

// ---------------------------------------------------------------------------
// x -> bf16 hi/lo planes (once per launch); 8 elems/thread, 16B stores.
// ---------------------------------------------------------------------------
__global__ __launch_bounds__(256) void k_castx(const float* __restrict__ x,
                                               unsigned short* __restrict__ xH,
                                               unsigned short* __restrict__ xL) {
  int i = blockIdx.x * 256 + threadIdx.x;  // 1,048,576 threads x 8 elems
  const float4* x4 = (const float4*)x;
  float4 a = x4[i * 2 + 0];
  float4 b = x4[i * 2 + 1];
  uint2 ha = pack4bf(a, 0), hb = pack4bf(b, 0);
  uint2 la = pack4bf(a, 1), lb = pack4bf(b, 1);
  uint4 hv; hv.x = ha.x; hv.y = ha.y; hv.z = hb.x; hv.w = hb.y;
  uint4 lv; lv.x = la.x; lv.y = la.y; lv.z = lb.x; lv.w = lb.y;
  *(uint4*)&xH[i * 8] = hv;
  *(uint4*)&xL[i * 8] = lv;
}

// ---------------------------------------------------------------------------
// CSR build (by dst) so the per-step aggregation is an atomic-free gather
// ---------------------------------------------------------------------------
__global__ __launch_bounds__(256) void k_hist(const int* __restrict__ dst, int* __restrict__ cnt) {
  int e = blockIdx.x * 256 + threadIdx.x;
  if (e < EE) atomicAdd(&cnt[dst[e]], 1);
}

__global__ __launch_bounds__(1024) void k_scan(const int* __restrict__ cnt,
                                               int* __restrict__ rowptr,
                                               int* __restrict__ cursor) {
  __shared__ int part[1024];
  int t = threadIdx.x;
  int base = t * 64;
  int s = 0;
  for (int i = 0; i < 64; i++) s += cnt[base + i];
  part[t] = s;
  __syncthreads();
  for (int off = 1; off < 1024; off <<= 1) {
    int v = part[t];
    int u = (t >= off) ? part[t - off] : 0;
    __syncthreads();
    part[t] = v + u;
    __syncthreads();
  }
  int run = part[t] - s;  // exclusive prefix of this chunk
  for (int i = 0; i < 64; i++) {
    rowptr[base + i] = run;
    cursor[base + i] = run;
    run += cnt[base + i];
  }
  if (t == 1023) rowptr[NN] = run;
}

__global__ __launch_bounds__(256) void k_fill(const int* __restrict__ src,
                                              const int* __restrict__ dst,
                                              const float* __restrict__ ew,
                                              int* __restrict__ cursor,
                                              int* __restrict__ col,
                                              float* __restrict__ wgt) {
  int e = blockIdx.x * 256 + threadIdx.x;
  if (e < EE) {
    int d = dst[e];
    int p = atomicAdd(&cursor[d], 1);
    col[p] = src[e];
    wgt[p] = ew[e];
  }
}

// ---------------------------------------------------------------------------
// m = h @ W via split-bf16 MFMA; A pre-split bf16 hi/lo planes.
// Staging via async global_load_lds(16B): LDS linear (no pad), XOR-swizzled
// on the GLOBAL source side (LDS[row][c] = src[row][c^(row&7)]); reads use
// the matching XOR -> conflict-free (2-way max). Pass order: hh, hl, lh.
// ---------------------------------------------------------------------------
__global__ __launch_bounds__(256, 4) void k_gemm_mfma(
    const unsigned short* __restrict__ Ah, const unsigned short* __restrict__ Al,
    const unsigned short* __restrict__ Wh, const unsigned short* __restrict__ Wl,
    float* __restrict__ Cout) {
  __shared__ __attribute__((aligned(16))) unsigned short As[64 * 128];
  int t = threadIdx.x;
  int r0 = blockIdx.x * 64;
  int wv = t >> 6, lane = t & 63;
  int ln = lane & 15, q = lane >> 4;
  f4acc acc[4][2];
#pragma unroll
  for (int mt = 0; mt < 4; mt++)
#pragma unroll
    for (int nt = 0; nt < 2; nt++) acc[mt][nt] = (f4acc)0.f;

  for (int p = 0; p < 3; p++) {
    if (p != 1) {  // stage A full K (hi at p0, lo at p2): 4 async 16B DMAs/thread
      const unsigned short* S = (p == 2) ? Al : Ah;
      if (p) __syncthreads();
#pragma unroll
      for (int it = 0; it < 4; it++) {
        int v8 = it * 256 + t;
        int row = v8 >> 4, c = v8 & 15;
        int csrc = c ^ (row & 7);
        gload_lds16(&S[(r0 + row) * 128 + csrc * 8], &As[v8 * 8]);
      }
      __syncthreads();  // drains vmcnt for the lds loads
    }
    const unsigned short* W = (p == 1) ? Wl : Wh;
#pragma unroll
    for (int k0 = 0; k0 < 128; k0 += 32) {
      s8bf af[4], bf[2];
#pragma unroll
      for (int nt = 0; nt < 2; nt++)
        bf[nt] = *(const s8bf*)&W[(wv * 32 + nt * 16 + ln) * 128 + k0 + q * 8];
#pragma unroll
      for (int mt = 0; mt < 4; mt++) {
        int ck = ((k0 >> 3) + q) ^ (ln & 7);
        af[mt] = *(const s8bf*)&As[(mt * 16 + ln) * 128 + (ck << 3)];
      }
#pragma unroll
      for (int mt = 0; mt < 4; mt++)
#pragma unroll
        for (int nt = 0; nt < 2; nt++)
          acc[mt][nt] = __builtin_amdgcn_mfma_f32_16x16x32_bf16(af[mt], bf[nt], acc[mt][nt], 0, 0, 0);
    }
  }
#pragma unroll
  for (int mt = 0; mt < 4; mt++)
#pragma unroll
    for (int nt = 0; nt < 2; nt++)
#pragma unroll
      for (int reg = 0; reg < 4; reg++) {
        int r = r0 + mt * 16 + q * 4 + reg;
        Cout[r * 128 + wv * 32 + nt * 16 + ln] = acc[mt][nt][reg];
      }
}

// ---------------------------------------------------------------------------
// agg[n,:] = sum over in-edges of m[src,:]*w.  Emits agg directly as bf16
// hi/lo planes (identical bits to what the GRU staging used to compute).
// (R1-exact.)
// ---------------------------------------------------------------------------
__global__ __launch_bounds__(256) void k_gather(const float* __restrict__ m,
                                                const int* __restrict__ rowptr,
                                                const int* __restrict__ col,
                                                const float* __restrict__ wgt,
                                                unsigned short* __restrict__ aggH,
                                                unsigned short* __restrict__ aggL) {
  int t = threadIdx.x;
  int n = blockIdx.x * 8 + (t >> 5);
  int c4 = t & 31;
  const float4* m4 = (const float4*)m;
  int s0 = rowptr[n], s1 = rowptr[n + 1];
  float ax = 0.f, ay = 0.f, az = 0.f, aw = 0.f;
  int e = s0;
  for (; e + 2 <= s1; e += 2) {
    int cA = col[e], cB = col[e + 1];
    float wA = wgt[e], wB = wgt[e + 1];
    float4 vA = m4[cA * 32 + c4];
    float4 vB = m4[cB * 32 + c4];
    ax += vA.x * wA + vB.x * wB;
    ay += vA.y * wA + vB.y * wB;
    az += vA.z * wA + vB.z * wB;
    aw += vA.w * wA + vB.w * wB;
  }
  if (e < s1) {
    int cA = col[e];
    float wA = wgt[e];
    float4 vA = m4[cA * 32 + c4];
    ax += vA.x * wA; ay += vA.y * wA; az += vA.z * wA; aw += vA.w * wA;
  }
  unsigned short h0 = f2bf(ax), h1 = f2bf(ay), h2 = f2bf(az), h3 = f2bf(aw);
  unsigned short l0 = f2bf(ax - bf2f(h0)), l1 = f2bf(ay - bf2f(h1));
  unsigned short l2 = f2bf(az - bf2f(h2)), l3 = f2bf(aw - bf2f(h3));
  uint2 hpk, lpk;
  hpk.x = (unsigned)h0 | ((unsigned)h1 << 16); hpk.y = (unsigned)h2 | ((unsigned)h3 << 16);
  lpk.x = (unsigned)l0 | ((unsigned)l1 << 16); lpk.y = (unsigned)l2 | ((unsigned)l3 << 16);
  int base = n * 128 + c4 * 4;
  *(uint2*)&aggH[base] = hpk;
  *(uint2*)&aggL[base] = lpk;
}

// ---------------------------------------------------------------------------
// Fused dual GEMM + GRU via split-bf16 MFMA; both A matrices as bf16 hi/lo
// planes. Staging via async global_load_lds(16B), LDS linear + source-side
// XOR swizzle (same scheme as k_gemm_mfma). Output bf16 hi/lo planes;
// hold reconstructed hi+lo. grid (1024,2); NOT in-place.
// ---------------------------------------------------------------------------
__global__ __launch_bounds__(256, 2) void k_gru_mfma(
    const unsigned short* __restrict__ aggH, const unsigned short* __restrict__ aggL,
    const unsigned short* __restrict__ hinH, const unsigned short* __restrict__ hinL,
    const unsigned short* __restrict__ wihCh, const unsigned short* __restrict__ wihCl,
    const unsigned short* __restrict__ whhCh, const unsigned short* __restrict__ whhCl,
    const float* __restrict__ bih, const float* __restrict__ bhh,
    unsigned short* __restrict__ houtH, unsigned short* __restrict__ houtL) {
  __shared__ __attribute__((aligned(16))) unsigned short As[2 * 64 * 128];  // [mat][row][k]
  int t = threadIdx.x;
  int r0 = blockIdx.x * 64;
  int d0 = blockIdx.y * 64;
  int wv = t >> 6, lane = t & 63;
  int ln = lane & 15, q = lane >> 4;
  f4acc acc[4][6];
#pragma unroll
  for (int mt = 0; mt < 4; mt++)
#pragma unroll
    for (int tg = 0; tg < 6; tg++) acc[mt][tg] = (f4acc)0.f;

  for (int p = 0; p < 3; p++) {
    if (p != 1) {  // stage both A mats full K: hi at p0, lo at p2
      const unsigned short* s0 = (p == 2) ? aggL : aggH;
      const unsigned short* s1 = (p == 2) ? hinL : hinH;
      if (p) __syncthreads();
#pragma unroll
      for (int it = 0; it < 8; it++) {
        int v8 = it * 256 + t;          // 0..2047; mat uniform per it
        int mat = v8 >> 10;
        int row = (v8 >> 4) & 63, c = v8 & 15;
        int csrc = c ^ (row & 7);
        const unsigned short* S = mat ? s1 : s0;
        gload_lds16(&S[(r0 + row) * 128 + csrc * 8], &As[v8 * 8]);
      }
      __syncthreads();  // drains vmcnt for the lds loads
    }
    const unsigned short* wx = (p == 1) ? wihCl : wihCh;
    const unsigned short* wh = (p == 1) ? whhCl : whhCh;
#pragma unroll
    for (int k0 = 0; k0 < 128; k0 += 32) {
      s8bf af[2][4], bfr[6];
#pragma unroll
      for (int tg = 0; tg < 6; tg++) {
        int gate = (tg < 3) ? tg : tg - 3;
        const unsigned short* W = (tg < 3) ? wx : wh;
        bfr[tg] = *(const s8bf*)&W[(gate * 128 + d0 + wv * 16 + ln) * 128 + k0 + q * 8];
      }
      int ck = ((k0 >> 3) + q) ^ (ln & 7);
#pragma unroll
      for (int mat = 0; mat < 2; mat++)
#pragma unroll
        for (int mt = 0; mt < 4; mt++)
          af[mat][mt] = *(const s8bf*)&As[mat * 8192 + (mt * 16 + ln) * 128 + (ck << 3)];
#pragma unroll
      for (int mt = 0; mt < 4; mt++)
#pragma unroll
        for (int tg = 0; tg < 6; tg++)
          acc[mt][tg] = __builtin_amdgcn_mfma_f32_16x16x32_bf16(
              af[tg < 3 ? 0 : 1][mt], bfr[tg], acc[mt][tg], 0, 0, 0);
    }
  }
  int d = d0 + wv * 16 + ln;
  float bi0 = bih[d], bi1 = bih[128 + d], bi2 = bih[256 + d];
  float bh0 = bhh[d], bh1 = bhh[128 + d], bh2 = bhh[256 + d];
#pragma unroll
  for (int mt = 0; mt < 4; mt++) {
#pragma unroll
    for (int reg = 0; reg < 4; reg++) {
      int r = r0 + mt * 16 + q * 4 + reg;
      int idx = r * 128 + d;
      float hold = bf2f(hinH[idx]) + bf2f(hinL[idx]);
      float xr = acc[mt][0][reg] + bi0;
      float xz = acc[mt][1][reg] + bi1;
      float xn = acc[mt][2][reg] + bi2;
      float hr = acc[mt][3][reg] + bh0;
      float hz = acc[mt][4][reg] + bh1;
      float hn = acc[mt][5][reg] + bh2;
      float rr = 1.f / (1.f + expf(-(xr + hr)));
      float zz = 1.f / (1.f + expf(-(xz + hz)));
      float nnv = tanhf(xn + rr * hn);
      float hv = (1.f - zz) * nnv + zz * hold;
      unsigned short hh = f2bf(hv);
      houtH[idx] = hh;
      houtL[idx] = f2bf(hv - bf2f(hh));
    }
  }
}

// ---------------------------------------------------------------------------
// Generic implicit-GEMM conv via split-bf16 MFMA. (R1-exact structure —
// measured best: full-K staging, NT=2, 1-deep B prefetch, 64x128 block.)
// Inputs pre-split bf16 hi/lo planes (plane A ch<WA, plane B ch>=WA).
// Weights [tap][co][ci] bf16 hi/lo. Output [g][Lco][CIN] f32 + per-co stats.
// Block: 64 l-rows x 128 co; grid (ceil(Lco/64), CIN/128, G).
// ---------------------------------------------------------------------------
template<int CIN, int TAPS, int WA>
__global__ __launch_bounds__(256, 4) void k_conv_mfma(
    const unsigned short* __restrict__ hiA, const unsigned short* __restrict__ hiB,
    const unsigned short* __restrict__ loA, const unsigned short* __restrict__ loB,
    const unsigned short* __restrict__ Wh, const unsigned short* __restrict__ Wl,
    const float* __restrict__ bias, float* __restrict__ out,
    float* __restrict__ stats, int Lin, int Lco) {
  constexpr int APAD = CIN + 8;
  constexpr int ROWS = 64 + TAPS - 1;
  constexpr int NCH = CIN / 32;
  constexpr int TOT8 = ROWS * CIN / 8;       // 16B chunks to stage
  constexpr int NIT = (TOT8 + 255) / 256;
  constexpr int NINNER = TAPS * NCH;
  __shared__ __attribute__((aligned(16))) unsigned short As[ROWS * APAD];
  __shared__ float sred[256];
  const int g = blockIdx.z, co0 = blockIdx.y * 128, l0 = blockIdx.x * 64;
  const int t = threadIdx.x;
  const int wv = t >> 6, lane = t & 63, ln = lane & 15, q = lane >> 4;
  f4acc acc[4][2];
#pragma unroll
  for (int mt = 0; mt < 4; mt++)
#pragma unroll
    for (int nt = 0; nt < 2; nt++) acc[mt][nt] = (f4acc)0.f;

  // pass order: (Ah,Bh), (Ah,Bl), (Al,Bh)
  for (int p = 0; p < 3; p++) {
    if (p != 1) {
      const unsigned short* pA = (p == 2) ? loA : hiA;
      const unsigned short* pB = (p == 2) ? loB : hiB;
      if (p) __syncthreads();
#pragma unroll
      for (int it = 0; it < NIT; it++) {
        int v8 = it * 256 + t;
        if (NIT * 256 == TOT8 || v8 < TOT8) {
          int row = (v8 * 8) / CIN, ch = (v8 * 8) % CIN;
          int lr = l0 + row; if (lr > Lin - 1) lr = Lin - 1;
          uint4 v;
          if (ch < WA) v = *(const uint4*)&pA[(g * Lin + lr) * WA + ch];
          else         v = *(const uint4*)&pB[(g * Lin + lr) * WA + ch - WA];
          *(uint4*)&As[row * APAD + ch] = v;
        }
      }
      __syncthreads();
    }
    const unsigned short* W = (p == 1) ? Wl : Wh;
    // flat (tap, ch) loop with 1-deep B prefetch (B loads are the latency pole)
    s8bf bcur[2], bnxt[2];
#pragma unroll
    for (int nt = 0; nt < 2; nt++)
      bcur[nt] = *(const s8bf*)&W[(co0 + wv * 32 + nt * 16 + ln) * CIN + q * 8];
#pragma unroll
    for (int it = 0; it < NINNER; it++) {
      const int tap = it / NCH, ch = it % NCH;
      if (it + 1 < NINNER) {
        const int ntap = (it + 1) / NCH, nch = (it + 1) % NCH;
#pragma unroll
        for (int nt = 0; nt < 2; nt++)
          bnxt[nt] = *(const s8bf*)&W[(ntap * CIN + co0 + wv * 32 + nt * 16 + ln) * CIN + nch * 32 + q * 8];
      }
      const int c0 = ch * 32;
      s8bf af[4];
#pragma unroll
      for (int mt = 0; mt < 4; mt++)
        af[mt] = *(const s8bf*)&As[(mt * 16 + ln + tap) * APAD + c0 + q * 8];
#pragma unroll
      for (int mt = 0; mt < 4; mt++)
#pragma unroll
        for (int nt = 0; nt < 2; nt++)
          acc[mt][nt] = __builtin_amdgcn_mfma_f32_16x16x32_bf16(af[mt], bcur[nt], acc[mt][nt], 0, 0, 0);
      if (it + 1 < NINNER) { bcur[0] = bnxt[0]; bcur[1] = bnxt[1]; }
    }
  }
  // epilogue: bias, store [g][l][co], per-co sum/sumsq
  sred[t] = 0.f;
  __syncthreads();
#pragma unroll
  for (int nt = 0; nt < 2; nt++) {
    int cl = wv * 32 + nt * 16 + ln;
    int co = co0 + cl;
    float bv = bias[co];
    float s = 0.f, s2 = 0.f;
#pragma unroll
    for (int mt = 0; mt < 4; mt++)
#pragma unroll
      for (int reg = 0; reg < 4; reg++) {
        int l = l0 + mt * 16 + q * 4 + reg;
        if (l < Lco) {
          float v = acc[mt][nt][reg] + bv;
          out[(g * Lco + l) * CIN + co] = v;
          s += v; s2 += v * v;
        }
      }
    atomicAdd(&sred[cl], s);
    atomicAdd(&sred[128 + cl], s2);
  }
  __syncthreads();
  if (t < 128) atomicAdd(&stats[co0 + t], sred[t]);
  else atomicAdd(&stats[CIN + co0 + (t - 128)], sred[t]);
}

// ---------------------------------------------------------------------------
// BN(training stats) -> ReLU -> maxpool(pk, stride 2); l-major both sides.
// PLANES=true: emit bf16 hi/lo planes (for 1x1 conv input);
// PLANES=false: emit f32 (for k_final).
// ---------------------------------------------------------------------------
template<bool PLANES>
__global__ __launch_bounds__(256) void k_bnpool(const float* __restrict__ in,
                                                float* __restrict__ outF,
                                                unsigned short* __restrict__ outH,
                                                unsigned short* __restrict__ outL,
                                                const float* __restrict__ stats,
                                                const float* __restrict__ gamma,
                                                const float* __restrict__ beta,
                                                int Cch, int LinC, int Lout, int pk) {
  int idx = blockIdx.x * 256 + threadIdx.x;
  int total = GG * Cch * Lout;
  if (idx >= total) return;
  int c = idx & (Cch - 1);
  int r = idx / Cch;
  int p = r % Lout;
  int g = r / Lout;
  float cntf = (float)(GG * LinC);
  float mean = stats[c] / cntf;
  float var = stats[Cch + c] / cntf - mean * mean;
  float inv = rsqrtf(var + 1e-5f) * gamma[c];
  float sh = beta[c] - mean * inv;
  const float* base = &in[((g * LinC) + 2 * p) * Cch + c];
  float m = 0.f;  // relu output >= 0
  for (int k = 0; k < pk; k++) {
    float v = fmaxf(base[k * Cch] * inv + sh, 0.f);
    m = fmaxf(m, v);
  }
  int o = (g * Lout + p) * Cch + c;
  if (PLANES) {
    unsigned short hh = f2bf(m);
    outH[o] = hh;
    outL[o] = f2bf(m - bf2f(hh));
  } else {
    outF[o] = m;
  }
}

// ---------------------------------------------------------------------------
// final: Y2 [g][127][128], Z2 [g][127][256] l-major f32
// ---------------------------------------------------------------------------
__global__ __launch_bounds__(128) void k_final(const float* __restrict__ Y2,
                                               const float* __restrict__ Z2,
                                               const float* __restrict__ myw,
                                               const float* __restrict__ myb,
                                               const float* __restrict__ mzw,
                                               const float* __restrict__ mzb,
                                               float* __restrict__ outp) {
  __shared__ float red0[128];
  __shared__ float red1[128];
  int g = blockIdx.x;
  int t = threadIdx.x;
  float y0 = myb[0], y1 = myb[1], z0 = mzb[0], z1 = mzb[1];
  if (t < P2) {
    const float* yb = &Y2[(g * P2 + t) * 128];
    for (int c = 0; c < 128; c++) {
      float v = yb[c];
      y0 += v * myw[c];
      y1 += v * myw[128 + c];
    }
    const float* zb = &Z2[(g * P2 + t) * 256];
    for (int c = 0; c < 256; c++) {
      float v = zb[c];
      z0 += v * mzw[c];
      z1 += v * mzw[256 + c];
    }
  }
  red0[t] = (t < P2) ? y0 * z0 : 0.f;
  red1[t] = (t < P2) ? y1 * z1 : 0.f;
  __syncthreads();
  for (int off = 64; off > 0; off >>= 1) {
    if (t < off) {
      red0[t] += red0[t + off];
      red1[t] += red1[t + off];
    }
    __syncthreads();
  }
  if (t == 0) {
    outp[g * 2 + 0] = red0[0] / 127.f;
    outp[g * 2 + 1] = red1[0] / 127.f;
  }
}

// ---------------------------------------------------------------------------
extern "C" void kernel_launch(void* const* d_in, const int* in_sizes, int n_in,
                              void* d_out, int out_size, void* d_ws, size_t ws_size,
                              hipStream_t stream) {
  const float* x   = (const float*)d_in[0];
  const int* ei    = (const int*)d_in[1];
  const float* ew  = (const float*)d_in[2];
  // d_in[3] = batch: arange(N)//L -> pure reshape, unused
  const float* gw  = (const float*)d_in[4];
  const float* wih = (const float*)d_in[5];
  const float* whh = (const float*)d_in[6];
  const float* bih = (const float*)d_in[7];
  const float* bhh = (const float*)d_in[8];
  const float* w1  = (const float*)d_in[9];
  const float* b1  = (const float*)d_in[10];
  const float* w2  = (const float*)d_in[11];
  const float* b2  = (const float*)d_in[12];
  const float* wc1 = (const float*)d_in[13];
  const float* bc1 = (const float*)d_in[14];
  const float* wc2 = (const float*)d_in[15];
  const float* bc2 = (const float*)d_in[16];
  const float* bn1g = (const float*)d_in[17];
  const float* bn1b = (const float*)d_in[18];
  const float* bn2g = (const float*)d_in[19];
  const float* bn2b = (const float*)d_in[20];
  const float* myw = (const float*)d_in[21];
  const float* myb = (const float*)d_in[22];
  const float* mzw = (const float*)d_in[23];
  const float* mzb = (const float*)d_in[24];
  float* out = (float*)d_out;

  // ---------------- workspace layout ----------------
  // Persistent region (lives across GGNN + conv phases):
  float* ws = (float*)d_ws;
  unsigned short* PH = (unsigned short*)ws;       // 8,388,608 us (h planes, ping; final h)
  unsigned short* PL = PH + 8388608;
  unsigned short* xH = PL + 8388608;              // x planes
  unsigned short* xL = xH + 8388608;
  unsigned short* c1h  = xL + 8388608;            // conv weights bf16
  unsigned short* c1l  = c1h + 49152;
  unsigned short* cc1h = c1l + 49152;
  unsigned short* cc1l = cc1h + 196608;
  unsigned short* c2h  = cc1l + 196608;
  unsigned short* c2l  = c2h + 16384;
  unsigned short* cc2h = c2l + 16384;
  unsigned short* cc2l = cc2h + 65536;
  float* stats = (float*)(cc2l + 65536);          // 512 f
  float* Y2 = stats + 512;                        // 2,080,768 f ([g][127][128] f32)
  float* Z2 = Y2 + 2080768;                       // 4,161,536 f ([g][127][256] f32)
  float* shared0 = Z2 + 4161536;
  // GGNN-phase view of shared region:
  unsigned short* QH = (unsigned short*)shared0;  // h planes, pong
  unsigned short* QL = QH + 8388608;
  float* m = (float*)(QL + 8388608);              // 8,388,608 f (gemm out / gather in)
  unsigned short* aggH = (unsigned short*)(m + 8388608);
  unsigned short* aggL = aggH + 8388608;
  unsigned short* wihCh = aggL + 8388608;         // GRU weights bf16
  unsigned short* wihCl = wihCh + 49152;
  unsigned short* whhCh = wihCl + 49152;
  unsigned short* whhCl = whhCh + 49152;
  unsigned short* gwTh = whhCl + 49152;           // 98,304 us x2
  unsigned short* gwTl = gwTh + 98304;
  int* cnt    = (int*)(gwTl + 98304);             // 65,536
  int* rowptr = cnt + 65536;                      // 65,537
  int* cursor = rowptr + 65537;                   // 65,536
  int* col    = cursor + 65536;                   // 262,144
  float* wgt  = (float*)(col + 262144);           // 262,144
  float* ggnn_end = wgt + 262144;
  // Conv-phase view of shared region (aliases GGNN buffers, all dead by then):
  float* bufA = shared0;                          // 16,711,680 f (conv out, l-major)
  unsigned short* bufBH = (unsigned short*)(bufA + 16711680);  // pool1 planes
  unsigned short* bufBL = bufBH + 8323072;
  float* conv_end = (float*)(bufBL + 8323072);
  float* wend = (ggnn_end > conv_end) ? ggnn_end : conv_end;
  size_t needed = (size_t)(wend - ws) * 4;
  if (ws_size < needed) return;

  const int* src = ei;
  const int* dst = ei + EE;

  // one-time prep per launch
  k_prep<<<768, 256, 0, stream>>>(wih, whh, gw, w1, wc1, w2, wc2,
                                  wihCh, wihCl, whhCh, whhCl, gwTh, gwTl,
                                  c1h, c1l, cc1h, cc1l, c2h, c2l, cc2h, cc2l);
  k_castx<<<4096, 256, 0, stream>>>(x, xH, xL);
  hipMemsetAsync(cnt, 0, 65536 * 4, stream);
  k_hist<<<1024, 256, 0, stream>>>(dst, cnt);
  k_scan<<<1, 1024, 0, stream>>>(cnt, rowptr, cursor);
  k_fill<<<1024, 256, 0, stream>>>(src, dst, ew, cursor, col, wgt);

  // GGNN: 6 steps, ping-pong h planes. s=0 in: x planes; s=5 out: P planes.
  for (int s = 0; s < NSTEPS; s++) {
    const unsigned short* AH = (s == 0) ? xH : ((s & 1) ? QH : PH);
    const unsigned short* AL = (s == 0) ? xL : ((s & 1) ? QL : PL);
    unsigned short* OH = (s & 1) ? PH : QH;
    unsigned short* OL = (s & 1) ? PL : QL;
    k_gemm_mfma<<<1024, 256, 0, stream>>>(AH, AL, gwTh + s * 16384, gwTl + s * 16384, m);
    k_gather<<<8192, 256, 0, stream>>>(m, rowptr, col, wgt, aggH, aggL);
    k_gru_mfma<<<dim3(1024, 2), 256, 0, stream>>>(aggH, aggL, AH, AL, wihCh, wihCl,
                                                  whhCh, whhCl, bih, bhh, OH, OL);
  }

  // Y path: conv3 -> bufA [g][510][128]; pool -> bufB planes [g][254][128];
  //         1x1 -> bufA [g][254][128]; pool -> Y2 f32 [g][127][128]
  hipMemsetAsync(stats, 0, 512 * 4, stream);
  k_conv_mfma<128, 3, 128><<<dim3(8, 1, 128), 256, 0, stream>>>(
      PH, nullptr, PL, nullptr, c1h, c1l, b1, bufA, stats, 512, L1);
  k_bnpool<true><<<(GG * 128 * P1 + 255) / 256, 256, 0, stream>>>(
      bufA, nullptr, bufBH, bufBL, stats, bn1g, bn1b, 128, L1, P1, 3);
  hipMemsetAsync(stats, 0, 512 * 4, stream);
  k_conv_mfma<128, 1, 128><<<dim3(4, 1, 128), 256, 0, stream>>>(
      bufBH, nullptr, bufBL, nullptr, c2h, c2l, b2, bufA, stats, P1, P1);
  k_bnpool<false><<<(GG * 128 * P2 + 255) / 256, 256, 0, stream>>>(
      bufA, Y2, nullptr, nullptr, stats, bn1g, bn1b, 128, P1, P2, 2);

  // Z path: conv3(concat h,x) -> bufA [g][510][256]; pool -> bufB planes;
  //         1x1 -> bufA [g][254][256]; pool -> Z2 f32 [g][127][256]
  hipMemsetAsync(stats, 0, 512 * 4, stream);
  k_conv_mfma<256, 3, 128><<<dim3(8, 2, 128), 256, 0, stream>>>(
      PH, xH, PL, xL, cc1h, cc1l, bc1, bufA, stats, 512, L1);
  k_bnpool<true><<<(GG * 256 * P1 + 255) / 256, 256, 0, stream>>>(
      bufA, nullptr, bufBH, bufBL, stats, bn2g, bn2b, 256, L1, P1, 3);
  hipMemsetAsync(stats, 0, 512 * 4, stream);
  k_conv_mfma<256, 1, 256><<<dim3(4, 2, 128), 256, 0, stream>>>(
      bufBH, nullptr, bufBL, nullptr, cc2h, cc2l, bc2, bufA, stats, P1, P1);
  k_bnpool<false><<<(GG * 256 * P2 + 255) / 256, 256, 0, stream>>>(
      bufA, Z2, nullptr, nullptr, stats, bn2g, bn2b, 256, P1, P2, 2);

  // epilogue
  k_final<<<128, 128, 0, stream>>>(Y2, Z2, myw, myb, mzw, mzb, out);
}

// Round 8
// 1471.180 us; speedup vs baseline: 1.4708x; 1.1107x over previous
//
#include <hip/hip_runtime.h>
#include <math.h>

// Problem constants
#define NN 65536   // nodes
#define GG 128     // graphs
#define LL 512     // nodes per graph
#define DD 128     // feature dim
#define EE 262144  // edges
#define NSTEPS 6
#define CC 256     // concat dim
#define L1 510     // after k=3 valid conv
#define P1 254     // after pool(3,2)
#define P2 127     // after pool(2,2)

typedef __attribute__((ext_vector_type(8))) short s8bf;   // 8 bf16 in 4 VGPRs
typedef __attribute__((ext_vector_type(4))) float f4acc;  // MFMA accumulator

// fp32 -> bf16 (RNE) and back, as raw ushort
__device__ __forceinline__ unsigned short f2bf(float x) {
  unsigned u = __float_as_uint(x);
  unsigned r = u + 0x7FFFu + ((u >> 16) & 1u);
  return (unsigned short)(r >> 16);
}
__device__ __forceinline__ float bf2f(unsigned short h) {
  return __uint_as_float(((unsigned)h) << 16);
}
__device__ __forceinline__ unsigned short f2bf_sel(float x, int lo_sel) {
  unsigned short hi = f2bf(x);
  if (!lo_sel) return hi;
  return f2bf(x - bf2f(hi));
}
__device__ __forceinline__ uint2 pack4bf(float4 v, int lo_sel) {
  unsigned short s0 = f2bf_sel(v.x, lo_sel), s1 = f2bf_sel(v.y, lo_sel);
  unsigned short s2 = f2bf_sel(v.z, lo_sel), s3 = f2bf_sel(v.w, lo_sel);
  uint2 pk; pk.x = (unsigned)s0 | ((unsigned)s1 << 16);
  pk.y = (unsigned)s2 | ((unsigned)s3 << 16);
  return pk;
}

// ---------------------------------------------------------------------------
// prep: all weights to bf16 hi/lo in MFMA layouts.
// ---------------------------------------------------------------------------
__global__ __launch_bounds__(256) void k_prep(
    const float* __restrict__ wih, const float* __restrict__ whh,
    const float* __restrict__ gw,
    const float* __restrict__ w1, const float* __restrict__ wc1,
    const float* __restrict__ w2, const float* __restrict__ wc2,
    unsigned short* __restrict__ whhCh, unsigned short* __restrict__ whhCl,
    unsigned short* __restrict__ c1h, unsigned short* __restrict__ c1l,
    unsigned short* __restrict__ cc1h, unsigned short* __restrict__ cc1l,
    unsigned short* __restrict__ c2h, unsigned short* __restrict__ c2l,
    unsigned short* __restrict__ cc2h, unsigned short* __restrict__ cc2l) {
  int i = blockIdx.x * 256 + threadIdx.x;
  if (i < 49152) {  // GRU h-gate weights, elementwise hi/lo (already [384][128])
    float u = whh[i];
    unsigned short h2 = f2bf(u);
    whhCh[i] = h2; whhCl[i] = f2bf(u - bf2f(h2));
  }
  if (i < 49152) {  // c1: i = (tap*128+co)*128+ci ; src w1[co][ci][tap]
    int ci = i & 127; int r = i >> 7; int co = r & 127; int tap = r >> 7;
    float v = w1[(co * 128 + ci) * 3 + tap];
    unsigned short h_ = f2bf(v);
    c1h[i] = h_; c1l[i] = f2bf(v - bf2f(h_));
  }
  if (i < 196608) {  // cc1: i = (tap*256+co)*256+ci ; src wc1[co][ci][tap]
    int ci = i & 255; int r = i >> 8; int co = r & 255; int tap = r >> 8;
    float v = wc1[(co * 256 + ci) * 3 + tap];
    unsigned short h_ = f2bf(v);
    cc1h[i] = h_; cc1l[i] = f2bf(v - bf2f(h_));
  }
  if (i < 16384) {  // c2: identity layout [co][ci]
    float v = w2[i];
    unsigned short h_ = f2bf(v);
    c2h[i] = h_; c2l[i] = f2bf(v - bf2f(h_));
  }
  if (i < 65536) {  // cc2: identity layout [co][ci]
    float v = wc2[i];
    unsigned short h_ = f2bf(v);
    cc2h[i] = h_; cc2l[i] = f2bf(v - bf2f(h_));
  }
}

// ---------------------------------------------------------------------------
// combine: Wc_s = gw_s . wih^T  (folds the GGNN linear into the GRU x-gates).
// Wc[s][d][k] = sum_c gw[s][k][c] * wih[d][c];  layout [s][d=384][k=128],
// emitted as bf16 hi/lo planes. 294,912 outputs, 128-MAC loop each (L2-hot).
// ---------------------------------------------------------------------------
__global__ __launch_bounds__(256) void k_combine(
    const float* __restrict__ gw, const float* __restrict__ wih,
    unsigned short* __restrict__ WcH, unsigned short* __restrict__ WcL) {
  int i = blockIdx.x * 256 + threadIdx.x;  // < 294912
  int s = i / 49152;
  int r = i % 49152;
  int d = r >> 7, k = r & 127;
  const float4* ga = (const float4*)&gw[(s << 14) + k * 128];
  const float4* wa = (const float4*)&wih[d * 128];
  float4 av = make_float4(0.f, 0.f, 0.f, 0.f);
#pragma unroll 8
  for (int c = 0; c < 32; c++) {
    float4 g4 = ga[c], w4 = wa[c];
    av.x += g4.x * w4.x; av.y += g4.y * w4.y;
    av.z += g4.z * w4.z; av.w += g4.w * w4.w;
  }
  float acc = (av.x + av.y) + (av.z + av.w);
  unsigned short h_ = f2bf(acc);
  WcH[i] = h_;
  WcL[i] = f2bf(acc - bf2f(h_));
}

// ---------------------------------------------------------------------------
// x -> bf16 hi/lo planes (once per launch); 8 elems/thread, 16B stores.
// ---------------------------------------------------------------------------
__global__ __launch_bounds__(256) void k_castx(const float* __restrict__ x,
                                               unsigned short* __restrict__ xH,
                                               unsigned short* __restrict__ xL) {
  int i = blockIdx.x * 256 + threadIdx.x;  // 1,048,576 threads x 8 elems
  const float4* x4 = (const float4*)x;
  float4 a = x4[i * 2 + 0];
  float4 b = x4[i * 2 + 1];
  uint2 ha = pack4bf(a, 0), hb = pack4bf(b, 0);
  uint2 la = pack4bf(a, 1), lb = pack4bf(b, 1);
  uint4 hv; hv.x = ha.x; hv.y = ha.y; hv.z = hb.x; hv.w = hb.y;
  uint4 lv; lv.x = la.x; lv.y = la.y; lv.z = lb.x; lv.w = lb.y;
  *(uint4*)&xH[i * 8] = hv;
  *(uint4*)&xL[i * 8] = lv;
}

// ---------------------------------------------------------------------------
// CSR build (by dst) so the per-step aggregation is an atomic-free gather
// ---------------------------------------------------------------------------
__global__ __launch_bounds__(256) void k_hist(const int* __restrict__ dst, int* __restrict__ cnt) {
  int e = blockIdx.x * 256 + threadIdx.x;
  if (e < EE) atomicAdd(&cnt[dst[e]], 1);
}

__global__ __launch_bounds__(1024) void k_scan(const int* __restrict__ cnt,
                                               int* __restrict__ rowptr,
                                               int* __restrict__ cursor) {
  __shared__ int part[1024];
  int t = threadIdx.x;
  int base = t * 64;
  int s = 0;
  for (int i = 0; i < 64; i++) s += cnt[base + i];
  part[t] = s;
  __syncthreads();
  for (int off = 1; off < 1024; off <<= 1) {
    int v = part[t];
    int u = (t >= off) ? part[t - off] : 0;
    __syncthreads();
    part[t] = v + u;
    __syncthreads();
  }
  int run = part[t] - s;  // exclusive prefix of this chunk
  for (int i = 0; i < 64; i++) {
    rowptr[base + i] = run;
    cursor[base + i] = run;
    run += cnt[base + i];
  }
  if (t == 1023) rowptr[NN] = run;
}

__global__ __launch_bounds__(256) void k_fill(const int* __restrict__ src,
                                              const int* __restrict__ dst,
                                              const float* __restrict__ ew,
                                              int* __restrict__ cursor,
                                              int* __restrict__ col,
                                              float* __restrict__ wgt) {
  int e = blockIdx.x * 256 + threadIdx.x;
  if (e < EE) {
    int d = dst[e];
    int p = atomicAdd(&cursor[d], 1);
    col[p] = src[e];
    wgt[p] = ew[e];
  }
}

// ---------------------------------------------------------------------------
// aggpre[n,:] = sum over in-edges of h[src,:]*w, reading h as bf16 hi/lo
// planes (hi+lo reconstruct, exact vs staged MFMA view). 32 lanes/node x
// 4 channels each (2x uint2 loads/plane), 8 nodes/block, 2-edge unroll.
// Emits aggpre as bf16 hi/lo planes (GRU A-operand format).
// ---------------------------------------------------------------------------
__global__ __launch_bounds__(256) void k_gather(
    const unsigned short* __restrict__ hH, const unsigned short* __restrict__ hL,
    const int* __restrict__ rowptr, const int* __restrict__ col,
    const float* __restrict__ wgt,
    unsigned short* __restrict__ aggH, unsigned short* __restrict__ aggL) {
  int t = threadIdx.x;
  int n = blockIdx.x * 8 + (t >> 5);
  int cb = (t & 31) * 4;  // channel base
  int s0 = rowptr[n], s1 = rowptr[n + 1];
  float ax = 0.f, ay = 0.f, az = 0.f, aw = 0.f;
  int e = s0;
  for (; e + 2 <= s1; e += 2) {
    int cA = col[e], cB = col[e + 1];
    float wA = wgt[e], wB = wgt[e + 1];
    uint2 hA = *(const uint2*)&hH[cA * 128 + cb];
    uint2 lA = *(const uint2*)&hL[cA * 128 + cb];
    uint2 hB = *(const uint2*)&hH[cB * 128 + cb];
    uint2 lB = *(const uint2*)&hL[cB * 128 + cb];
    float a0 = __uint_as_float(hA.x << 16) + __uint_as_float(lA.x << 16);
    float a1 = __uint_as_float(hA.x & 0xFFFF0000u) + __uint_as_float(lA.x & 0xFFFF0000u);
    float a2 = __uint_as_float(hA.y << 16) + __uint_as_float(lA.y << 16);
    float a3 = __uint_as_float(hA.y & 0xFFFF0000u) + __uint_as_float(lA.y & 0xFFFF0000u);
    float b0 = __uint_as_float(hB.x << 16) + __uint_as_float(lB.x << 16);
    float b1 = __uint_as_float(hB.x & 0xFFFF0000u) + __uint_as_float(lB.x & 0xFFFF0000u);
    float b2 = __uint_as_float(hB.y << 16) + __uint_as_float(lB.y << 16);
    float b3 = __uint_as_float(hB.y & 0xFFFF0000u) + __uint_as_float(lB.y & 0xFFFF0000u);
    ax += a0 * wA + b0 * wB;
    ay += a1 * wA + b1 * wB;
    az += a2 * wA + b2 * wB;
    aw += a3 * wA + b3 * wB;
  }
  if (e < s1) {
    int cA = col[e];
    float wA = wgt[e];
    uint2 hA = *(const uint2*)&hH[cA * 128 + cb];
    uint2 lA = *(const uint2*)&hL[cA * 128 + cb];
    float a0 = __uint_as_float(hA.x << 16) + __uint_as_float(lA.x << 16);
    float a1 = __uint_as_float(hA.x & 0xFFFF0000u) + __uint_as_float(lA.x & 0xFFFF0000u);
    float a2 = __uint_as_float(hA.y << 16) + __uint_as_float(lA.y << 16);
    float a3 = __uint_as_float(hA.y & 0xFFFF0000u) + __uint_as_float(lA.y & 0xFFFF0000u);
    ax += a0 * wA; ay += a1 * wA; az += a2 * wA; aw += a3 * wA;
  }
  unsigned short h0 = f2bf(ax), h1 = f2bf(ay), h2 = f2bf(az), h3 = f2bf(aw);
  unsigned short l0 = f2bf(ax - bf2f(h0)), l1 = f2bf(ay - bf2f(h1));
  unsigned short l2 = f2bf(az - bf2f(h2)), l3 = f2bf(aw - bf2f(h3));
  uint2 hpk, lpk;
  hpk.x = (unsigned)h0 | ((unsigned)h1 << 16); hpk.y = (unsigned)h2 | ((unsigned)h3 << 16);
  lpk.x = (unsigned)l0 | ((unsigned)l1 << 16); lpk.y = (unsigned)l2 | ((unsigned)l3 << 16);
  int base = n * 128 + cb;
  *(uint2*)&aggH[base] = hpk;
  *(uint2*)&aggL[base] = lpk;
}

// ---------------------------------------------------------------------------
// Fused dual GEMM + GRU via split-bf16 MFMA (R1-exact structure). x-gates use
// the per-step COMBINED weight Wc_s = gw_s . wih^T (so no separate m=h@W GEMM
// exists). Both A matrices arrive as bf16 hi/lo planes -> staging is 8 exact
// 16B copies/thread. Output bf16 hi/lo planes; hold = hi+lo. grid (1024,2).
// ---------------------------------------------------------------------------
__global__ __launch_bounds__(256, 2) void k_gru_mfma(
    const unsigned short* __restrict__ aggH, const unsigned short* __restrict__ aggL,
    const unsigned short* __restrict__ hinH, const unsigned short* __restrict__ hinL,
    const unsigned short* __restrict__ wxh, const unsigned short* __restrict__ wxl,
    const unsigned short* __restrict__ whhCh, const unsigned short* __restrict__ whhCl,
    const float* __restrict__ bih, const float* __restrict__ bhh,
    unsigned short* __restrict__ houtH, unsigned short* __restrict__ houtL) {
  __shared__ __attribute__((aligned(16))) unsigned short As[2 * 64 * 136];  // [mat][row][k]
  int t = threadIdx.x;
  int r0 = blockIdx.x * 64;
  int d0 = blockIdx.y * 64;
  int wv = t >> 6, lane = t & 63;
  int ln = lane & 15, q = lane >> 4;
  f4acc acc[4][6];
#pragma unroll
  for (int mt = 0; mt < 4; mt++)
#pragma unroll
    for (int tg = 0; tg < 6; tg++) acc[mt][tg] = (f4acc)0.f;

  for (int p = 0; p < 3; p++) {
    if (p != 1) {  // stage both A mats full K: hi at p0, lo at p2
      const unsigned short* s0 = (p == 2) ? aggL : aggH;
      const unsigned short* s1 = (p == 2) ? hinL : hinH;
      if (p) __syncthreads();
#pragma unroll
      for (int it = 0; it < 8; it++) {
        int v8 = it * 256 + t;          // 0..2047
        int mat = v8 >> 10;
        int row = (v8 >> 4) & 63, k = (v8 & 15) * 8;
        const unsigned short* S = mat ? s1 : s0;
        *(uint4*)&As[mat * 8704 + row * 136 + k] = *(const uint4*)&S[(r0 + row) * 128 + k];
      }
      __syncthreads();
    }
    const unsigned short* wx = (p == 1) ? wxl : wxh;
    const unsigned short* wh = (p == 1) ? whhCl : whhCh;
#pragma unroll
    for (int k0 = 0; k0 < 128; k0 += 32) {
      s8bf af[2][4], bfr[6];
#pragma unroll
      for (int tg = 0; tg < 6; tg++) {
        int gate = (tg < 3) ? tg : tg - 3;
        const unsigned short* W = (tg < 3) ? wx : wh;
        bfr[tg] = *(const s8bf*)&W[(gate * 128 + d0 + wv * 16 + ln) * 128 + k0 + q * 8];
      }
#pragma unroll
      for (int mat = 0; mat < 2; mat++)
#pragma unroll
        for (int mt = 0; mt < 4; mt++)
          af[mat][mt] = *(const s8bf*)&As[mat * 8704 + (mt * 16 + ln) * 136 + k0 + q * 8];
#pragma unroll
      for (int mt = 0; mt < 4; mt++)
#pragma unroll
        for (int tg = 0; tg < 6; tg++)
          acc[mt][tg] = __builtin_amdgcn_mfma_f32_16x16x32_bf16(
              af[tg < 3 ? 0 : 1][mt], bfr[tg], acc[mt][tg], 0, 0, 0);
    }
  }
  int d = d0 + wv * 16 + ln;
  float bi0 = bih[d], bi1 = bih[128 + d], bi2 = bih[256 + d];
  float bh0 = bhh[d], bh1 = bhh[128 + d], bh2 = bhh[256 + d];
#pragma unroll
  for (int mt = 0; mt < 4; mt++) {
#pragma unroll
    for (int reg = 0; reg < 4; reg++) {
      int r = r0 + mt * 16 + q * 4 + reg;
      int idx = r * 128 + d;
      float hold = bf2f(hinH[idx]) + bf2f(hinL[idx]);
      float xr = acc[mt][0][reg] + bi0;
      float xz = acc[mt][1][reg] + bi1;
      float xn = acc[mt][2][reg] + bi2;
      float hr = acc[mt][3][reg] + bh0;
      float hz = acc[mt][4][reg] + bh1;
      float hn = acc[mt][5][reg] + bh2;
      float rr = 1.f / (1.f + expf(-(xr + hr)));
      float zz = 1.f / (1.f + expf(-(xz + hz)));
      float nnv = tanhf(xn + rr * hn);
      float hv = (1.f - zz) * nnv + zz * hold;
      unsigned short hh = f2bf(hv);
      houtH[idx] = hh;
      houtL[idx] = f2bf(hv - bf2f(hh));
    }
  }
}

// ---------------------------------------------------------------------------
// Generic implicit-GEMM conv via split-bf16 MFMA. (R1-exact structure —
// measured best: full-K staging, NT=2, 1-deep B prefetch, 64x128 block.)
// Inputs pre-split bf16 hi/lo planes (plane A ch<WA, plane B ch>=WA).
// Weights [tap][co][ci] bf16 hi/lo. Output [g][Lco][CIN] f32 + per-co stats.
// Block: 64 l-rows x 128 co; grid (ceil(Lco/64), CIN/128, G).
// ---------------------------------------------------------------------------
template<int CIN, int TAPS, int WA>
__global__ __launch_bounds__(256, 4) void k_conv_mfma(
    const unsigned short* __restrict__ hiA, const unsigned short* __restrict__ hiB,
    const unsigned short* __restrict__ loA, const unsigned short* __restrict__ loB,
    const unsigned short* __restrict__ Wh, const unsigned short* __restrict__ Wl,
    const float* __restrict__ bias, float* __restrict__ out,
    float* __restrict__ stats, int Lin, int Lco) {
  constexpr int APAD = CIN + 8;
  constexpr int ROWS = 64 + TAPS - 1;
  constexpr int NCH = CIN / 32;
  constexpr int TOT8 = ROWS * CIN / 8;       // 16B chunks to stage
  constexpr int NIT = (TOT8 + 255) / 256;
  constexpr int NINNER = TAPS * NCH;
  __shared__ __attribute__((aligned(16))) unsigned short As[ROWS * APAD];
  __shared__ float sred[256];
  const int g = blockIdx.z, co0 = blockIdx.y * 128, l0 = blockIdx.x * 64;
  const int t = threadIdx.x;
  const int wv = t >> 6, lane = t & 63, ln = lane & 15, q = lane >> 4;
  f4acc acc[4][2];
#pragma unroll
  for (int mt = 0; mt < 4; mt++)
#pragma unroll
    for (int nt = 0; nt < 2; nt++) acc[mt][nt] = (f4acc)0.f;

  // pass order: (Ah,Bh), (Ah,Bl), (Al,Bh)
  for (int p = 0; p < 3; p++) {
    if (p != 1) {
      const unsigned short* pA = (p == 2) ? loA : hiA;
      const unsigned short* pB = (p == 2) ? loB : hiB;
      if (p) __syncthreads();
#pragma unroll
      for (int it = 0; it < NIT; it++) {
        int v8 = it * 256 + t;
        if (NIT * 256 == TOT8 || v8 < TOT8) {
          int row = (v8 * 8) / CIN, ch = (v8 * 8) % CIN;
          int lr = l0 + row; if (lr > Lin - 1) lr = Lin - 1;
          uint4 v;
          if (ch < WA) v = *(const uint4*)&pA[(g * Lin + lr) * WA + ch];
          else         v = *(const uint4*)&pB[(g * Lin + lr) * WA + ch - WA];
          *(uint4*)&As[row * APAD + ch] = v;
        }
      }
      __syncthreads();
    }
    const unsigned short* W = (p == 1) ? Wl : Wh;
    // flat (tap, ch) loop with 1-deep B prefetch (B loads are the latency pole)
    s8bf bcur[2], bnxt[2];
#pragma unroll
    for (int nt = 0; nt < 2; nt++)
      bcur[nt] = *(const s8bf*)&W[(co0 + wv * 32 + nt * 16 + ln) * CIN + q * 8];
#pragma unroll
    for (int it = 0; it < NINNER; it++) {
      const int tap = it / NCH, ch = it % NCH;
      if (it + 1 < NINNER) {
        const int ntap = (it + 1) / NCH, nch = (it + 1) % NCH;
#pragma unroll
        for (int nt = 0; nt < 2; nt++)
          bnxt[nt] = *(const s8bf*)&W[(ntap * CIN + co0 + wv * 32 + nt * 16 + ln) * CIN + nch * 32 + q * 8];
      }
      const int c0 = ch * 32;
      s8bf af[4];
#pragma unroll
      for (int mt = 0; mt < 4; mt++)
        af[mt] = *(const s8bf*)&As[(mt * 16 + ln + tap) * APAD + c0 + q * 8];
#pragma unroll
      for (int mt = 0; mt < 4; mt++)
#pragma unroll
        for (int nt = 0; nt < 2; nt++)
          acc[mt][nt] = __builtin_amdgcn_mfma_f32_16x16x32_bf16(af[mt], bcur[nt], acc[mt][nt], 0, 0, 0);
      if (it + 1 < NINNER) { bcur[0] = bnxt[0]; bcur[1] = bnxt[1]; }
    }
  }
  // epilogue: bias, store [g][l][co], per-co sum/sumsq
  sred[t] = 0.f;
  __syncthreads();
#pragma unroll
  for (int nt = 0; nt < 2; nt++) {
    int cl = wv * 32 + nt * 16 + ln;
    int co = co0 + cl;
    float bv = bias[co];
    float s = 0.f, s2 = 0.f;
#pragma unroll
    for (int mt = 0; mt < 4; mt++)
#pragma unroll
      for (int reg = 0; reg < 4; reg++) {
        int l = l0 + mt * 16 + q * 4 + reg;
        if (l < Lco) {
          float v = acc[mt][nt][reg] + bv;
          out[(g * Lco + l) * CIN + co] = v;
          s += v; s2 += v * v;
        }
      }
    atomicAdd(&sred[cl], s);
    atomicAdd(&sred[128 + cl], s2);
  }
  __syncthreads();
  if (t < 128) atomicAdd(&stats[co0 + t], sred[t]);
  else atomicAdd(&stats[CIN + co0 + (t - 128)], sred[t]);
}

// ---------------------------------------------------------------------------
// BN(training stats) -> ReLU -> maxpool(pk, stride 2); l-major both sides.
// PLANES=true: emit bf16 hi/lo planes (for 1x1 conv input);
// PLANES=false: emit f32 (for k_final).
// ---------------------------------------------------------------------------
template<bool PLANES>
__global__ __launch_bounds__(256) void k_bnpool(const float* __restrict__ in,
                                                float* __restrict__ outF,
                                                unsigned short* __restrict__ outH,
                                                unsigned short* __restrict__ outL,
                                                const float* __restrict__ stats,
                                                const float* __restrict__ gamma,
                                                const float* __restrict__ beta,
                                                int Cch, int LinC, int Lout, int pk) {
  int idx = blockIdx.x * 256 + threadIdx.x;
  int total = GG * Cch * Lout;
  if (idx >= total) return;
  int c = idx & (Cch - 1);
  int r = idx / Cch;
  int p = r % Lout;
  int g = r / Lout;
  float cntf = (float)(GG * LinC);
  float mean = stats[c] / cntf;
  float var = stats[Cch + c] / cntf - mean * mean;
  float inv = rsqrtf(var + 1e-5f) * gamma[c];
  float sh = beta[c] - mean * inv;
  const float* base = &in[((g * LinC) + 2 * p) * Cch + c];
  float m = 0.f;  // relu output >= 0
  for (int k = 0; k < pk; k++) {
    float v = fmaxf(base[k * Cch] * inv + sh, 0.f);
    m = fmaxf(m, v);
  }
  int o = (g * Lout + p) * Cch + c;
  if (PLANES) {
    unsigned short hh = f2bf(m);
    outH[o] = hh;
    outL[o] = f2bf(m - bf2f(hh));
  } else {
    outF[o] = m;
  }
}

// ---------------------------------------------------------------------------
// final: Y2 [g][127][128], Z2 [g][127][256] l-major f32
// ---------------------------------------------------------------------------
__global__ __launch_bounds__(128) void k_final(const float* __restrict__ Y2,
                                               const float* __restrict__ Z2,
                                               const float* __restrict__ myw,
                                               const float* __restrict__ myb,
                                               const float* __restrict__ mzw,
                                               const float* __restrict__ mzb,
                                               float* __restrict__ outp) {
  __shared__ float red0[128];
  __shared__ float red1[128];
  int g = blockIdx.x;
  int t = threadIdx.x;
  float y0 = myb[0], y1 = myb[1], z0 = mzb[0], z1 = mzb[1];
  if (t < P2) {
    const float* yb = &Y2[(g * P2 + t) * 128];
    for (int c = 0; c < 128; c++) {
      float v = yb[c];
      y0 += v * myw[c];
      y1 += v * myw[128 + c];
    }
    const float* zb = &Z2[(g * P2 + t) * 256];
    for (int c = 0; c < 256; c++) {
      float v = zb[c];
      z0 += v * mzw[c];
      z1 += v * mzw[256 + c];
    }
  }
  red0[t] = (t < P2) ? y0 * z0 : 0.f;
  red1[t] = (t < P2) ? y1 * z1 : 0.f;
  __syncthreads();
  for (int off = 64; off > 0; off >>= 1) {
    if (t < off) {
      red0[t] += red0[t + off];
      red1[t] += red1[t + off];
    }
    __syncthreads();
  }
  if (t == 0) {
    outp[g * 2 + 0] = red0[0] / 127.f;
    outp[g * 2 + 1] = red1[0] / 127.f;
  }
}

// ---------------------------------------------------------------------------
extern "C" void kernel_launch(void* const* d_in, const int* in_sizes, int n_in,
                              void* d_out, int out_size, void* d_ws, size_t ws_size,
                              hipStream_t stream) {
  const float* x   = (const float*)d_in[0];
  const int* ei    = (const int*)d_in[1];
  const float* ew  = (const float*)d_in[2];
  // d_in[3] = batch: arange(N)//L -> pure reshape, unused
  const float* gw  = (const float*)d_in[4];
  const float* wih = (const float*)d_in[5];
  const float* whh = (const float*)d_in[6];
  const float* bih = (const float*)d_in[7];
  const float* bhh = (const float*)d_in[8];
  const float* w1  = (const float*)d_in[9];
  const float* b1  = (const float*)d_in[10];
  const float* w2  = (const float*)d_in[11];
  const float* b2  = (const float*)d_in[12];
  const float* wc1 = (const float*)d_in[13];
  const float* bc1 = (const float*)d_in[14];
  const float* wc2 = (const float*)d_in[15];
  const float* bc2 = (const float*)d_in[16];
  const float* bn1g = (const float*)d_in[17];
  const float* bn1b = (const float*)d_in[18];
  const float* bn2g = (const float*)d_in[19];
  const float* bn2b = (const float*)d_in[20];
  const float* myw = (const float*)d_in[21];
  const float* myb = (const float*)d_in[22];
  const float* mzw = (const float*)d_in[23];
  const float* mzb = (const float*)d_in[24];
  float* out = (float*)d_out;

  // ---------------- workspace layout ----------------
  // Persistent region (lives across GGNN + conv phases):
  float* ws = (float*)d_ws;
  unsigned short* PH = (unsigned short*)ws;       // 8,388,608 us (h planes, ping; final h)
  unsigned short* PL = PH + 8388608;
  unsigned short* xH = PL + 8388608;              // x planes
  unsigned short* xL = xH + 8388608;
  unsigned short* c1h  = xL + 8388608;            // conv weights bf16
  unsigned short* c1l  = c1h + 49152;
  unsigned short* cc1h = c1l + 49152;
  unsigned short* cc1l = cc1h + 196608;
  unsigned short* c2h  = cc1l + 196608;
  unsigned short* c2l  = c2h + 16384;
  unsigned short* cc2h = c2l + 16384;
  unsigned short* cc2l = cc2h + 65536;
  float* stats = (float*)(cc2l + 65536);          // 512 f
  float* Y2 = stats + 512;                        // 2,080,768 f ([g][127][128] f32)
  float* Z2 = Y2 + 2080768;                       // 4,161,536 f ([g][127][256] f32)
  float* shared0 = Z2 + 4161536;
  // GGNN-phase view of shared region:
  unsigned short* QH = (unsigned short*)shared0;  // h planes, pong
  unsigned short* QL = QH + 8388608;
  unsigned short* WcCh = QL + 8388608;            // combined x-gate weights: 6 x [384][128]
  unsigned short* WcCl = WcCh + 294912;
  unsigned short* aggH = WcCl + 294912;           // aggpre planes
  unsigned short* aggL = aggH + 8388608;
  unsigned short* whhCh = aggL + 8388608;         // GRU h-gate weights bf16
  unsigned short* whhCl = whhCh + 49152;
  int* cnt    = (int*)(whhCl + 49152);            // 65,536
  int* rowptr = cnt + 65536;                      // 65,537
  int* cursor = rowptr + 65537;                   // 65,536
  int* col    = cursor + 65536;                   // 262,144
  float* wgt  = (float*)(col + 262144);           // 262,144
  float* ggnn_end = wgt + 262144;
  // Conv-phase view of shared region (aliases GGNN buffers, all dead by then):
  float* bufA = shared0;                          // 16,711,680 f (conv out, l-major)
  unsigned short* bufBH = (unsigned short*)(bufA + 16711680);  // pool1 planes
  unsigned short* bufBL = bufBH + 8323072;
  float* conv_end = (float*)(bufBL + 8323072);
  float* wend = (ggnn_end > conv_end) ? ggnn_end : conv_end;
  size_t needed = (size_t)(wend - ws) * 4;
  if (ws_size < needed) return;

  const int* src = ei;
  const int* dst = ei + EE;

  // one-time prep per launch
  k_prep<<<768, 256, 0, stream>>>(wih, whh, gw, w1, wc1, w2, wc2,
                                  whhCh, whhCl,
                                  c1h, c1l, cc1h, cc1l, c2h, c2l, cc2h, cc2l);
  k_combine<<<1152, 256, 0, stream>>>(gw, wih, WcCh, WcCl);
  k_castx<<<4096, 256, 0, stream>>>(x, xH, xL);
  hipMemsetAsync(cnt, 0, 65536 * 4, stream);
  k_hist<<<1024, 256, 0, stream>>>(dst, cnt);
  k_scan<<<1, 1024, 0, stream>>>(cnt, rowptr, cursor);
  k_fill<<<1024, 256, 0, stream>>>(src, dst, ew, cursor, col, wgt);

  // GGNN: 6 steps, ping-pong h planes. The per-step m=h@W GEMM is folded
  // into the GRU x-gate weight (Wc_s), so each step is gather + GRU only.
  for (int s = 0; s < NSTEPS; s++) {
    const unsigned short* AH = (s == 0) ? xH : ((s & 1) ? QH : PH);
    const unsigned short* AL = (s == 0) ? xL : ((s & 1) ? QL : PL);
    unsigned short* OH = (s & 1) ? PH : QH;
    unsigned short* OL = (s & 1) ? PL : QL;
    k_gather<<<8192, 256, 0, stream>>>(AH, AL, rowptr, col, wgt, aggH, aggL);
    k_gru_mfma<<<dim3(1024, 2), 256, 0, stream>>>(aggH, aggL, AH, AL,
                                                  WcCh + s * 49152, WcCl + s * 49152,
                                                  whhCh, whhCl, bih, bhh, OH, OL);
  }

  // Y path: conv3 -> bufA [g][510][128]; pool -> bufB planes [g][254][128];
  //         1x1 -> bufA [g][254][128]; pool -> Y2 f32 [g][127][128]
  hipMemsetAsync(stats, 0, 512 * 4, stream);
  k_conv_mfma<128, 3, 128><<<dim3(8, 1, 128), 256, 0, stream>>>(
      PH, nullptr, PL, nullptr, c1h, c1l, b1, bufA, stats, 512, L1);
  k_bnpool<true><<<(GG * 128 * P1 + 255) / 256, 256, 0, stream>>>(
      bufA, nullptr, bufBH, bufBL, stats, bn1g, bn1b, 128, L1, P1, 3);
  hipMemsetAsync(stats, 0, 512 * 4, stream);
  k_conv_mfma<128, 1, 128><<<dim3(4, 1, 128), 256, 0, stream>>>(
      bufBH, nullptr, bufBL, nullptr, c2h, c2l, b2, bufA, stats, P1, P1);
  k_bnpool<false><<<(GG * 128 * P2 + 255) / 256, 256, 0, stream>>>(
      bufA, Y2, nullptr, nullptr, stats, bn1g, bn1b, 128, P1, P2, 2);

  // Z path: conv3(concat h,x) -> bufA [g][510][256]; pool -> bufB planes;
  //         1x1 -> bufA [g][254][256]; pool -> Z2 f32 [g][127][256]
  hipMemsetAsync(stats, 0, 512 * 4, stream);
  k_conv_mfma<256, 3, 128><<<dim3(8, 2, 128), 256, 0, stream>>>(
      PH, xH, PL, xL, cc1h, cc1l, bc1, bufA, stats, 512, L1);
  k_bnpool<true><<<(GG * 256 * P1 + 255) / 256, 256, 0, stream>>>(
      bufA, nullptr, bufBH, bufBL, stats, bn2g, bn2b, 256, L1, P1, 3);
  hipMemsetAsync(stats, 0, 512 * 4, stream);
  k_conv_mfma<256, 1, 256><<<dim3(4, 2, 128), 256, 0, stream>>>(
      bufBH, nullptr, bufBL, nullptr, cc2h, cc2l, bc2, bufA, stats, P1, P1);
  k_bnpool<false><<<(GG * 256 * P2 + 255) / 256, 256, 0, stream>>>(
      bufA, Z2, nullptr, nullptr, stats, bn2g, bn2b, 256, P1, P2, 2);

  // epilogue
  k_final<<<128, 128, 0, stream>>>(Y2, Z2, myw, myb, mzw, mzb, out);
}

// Round 9
// 1446.379 us; speedup vs baseline: 1.4960x; 1.0171x over previous
//
#include <hip/hip_runtime.h>
#include <math.h>

// Problem constants
#define NN 65536   // nodes
#define GG 128     // graphs
#define LL 512     // nodes per graph
#define DD 128     // feature dim
#define EE 262144  // edges
#define NSTEPS 6
#define CC 256     // concat dim
#define L1 510     // after k=3 valid conv
#define P1 254     // after pool(3,2)
#define P2 127     // after pool(2,2)

typedef __attribute__((ext_vector_type(8))) short s8bf;   // 8 bf16 in 4 VGPRs
typedef __attribute__((ext_vector_type(4))) float f4acc;  // MFMA accumulator

// fp32 -> bf16 (RNE) and back, as raw ushort
__device__ __forceinline__ unsigned short f2bf(float x) {
  unsigned u = __float_as_uint(x);
  unsigned r = u + 0x7FFFu + ((u >> 16) & 1u);
  return (unsigned short)(r >> 16);
}
__device__ __forceinline__ float bf2f(unsigned short h) {
  return __uint_as_float(((unsigned)h) << 16);
}
__device__ __forceinline__ unsigned short f2bf_sel(float x, int lo_sel) {
  unsigned short hi = f2bf(x);
  if (!lo_sel) return hi;
  return f2bf(x - bf2f(hi));
}
__device__ __forceinline__ uint2 pack4bf(float4 v, int lo_sel) {
  unsigned short s0 = f2bf_sel(v.x, lo_sel), s1 = f2bf_sel(v.y, lo_sel);
  unsigned short s2 = f2bf_sel(v.z, lo_sel), s3 = f2bf_sel(v.w, lo_sel);
  uint2 pk; pk.x = (unsigned)s0 | ((unsigned)s1 << 16);
  pk.y = (unsigned)s2 | ((unsigned)s3 << 16);
  return pk;
}

// ---------------------------------------------------------------------------
// prep: all weights to bf16 hi/lo in MFMA layouts.
// ---------------------------------------------------------------------------
__global__ __launch_bounds__(256) void k_prep(
    const float* __restrict__ wih, const float* __restrict__ whh,
    const float* __restrict__ gw,
    const float* __restrict__ w1, const float* __restrict__ wc1,
    const float* __restrict__ w2, const float* __restrict__ wc2,
    unsigned short* __restrict__ whhCh, unsigned short* __restrict__ whhCl,
    unsigned short* __restrict__ c1h, unsigned short* __restrict__ c1l,
    unsigned short* __restrict__ cc1h, unsigned short* __restrict__ cc1l,
    unsigned short* __restrict__ c2h, unsigned short* __restrict__ c2l,
    unsigned short* __restrict__ cc2h, unsigned short* __restrict__ cc2l) {
  int i = blockIdx.x * 256 + threadIdx.x;
  if (i < 49152) {  // GRU h-gate weights, elementwise hi/lo (already [384][128])
    float u = whh[i];
    unsigned short h2 = f2bf(u);
    whhCh[i] = h2; whhCl[i] = f2bf(u - bf2f(h2));
  }
  if (i < 49152) {  // c1: i = (tap*128+co)*128+ci ; src w1[co][ci][tap]
    int ci = i & 127; int r = i >> 7; int co = r & 127; int tap = r >> 7;
    float v = w1[(co * 128 + ci) * 3 + tap];
    unsigned short h_ = f2bf(v);
    c1h[i] = h_; c1l[i] = f2bf(v - bf2f(h_));
  }
  if (i < 196608) {  // cc1: i = (tap*256+co)*256+ci ; src wc1[co][ci][tap]
    int ci = i & 255; int r = i >> 8; int co = r & 255; int tap = r >> 8;
    float v = wc1[(co * 256 + ci) * 3 + tap];
    unsigned short h_ = f2bf(v);
    cc1h[i] = h_; cc1l[i] = f2bf(v - bf2f(h_));
  }
  if (i < 16384) {  // c2: identity layout [co][ci]
    float v = w2[i];
    unsigned short h_ = f2bf(v);
    c2h[i] = h_; c2l[i] = f2bf(v - bf2f(h_));
  }
  if (i < 65536) {  // cc2: identity layout [co][ci]
    float v = wc2[i];
    unsigned short h_ = f2bf(v);
    cc2h[i] = h_; cc2l[i] = f2bf(v - bf2f(h_));
  }
}

// ---------------------------------------------------------------------------
// combine: Wc_s = gw_s . wih^T  (folds the GGNN linear into the GRU x-gates).
// Wc[s][d][k] = sum_c gw[s][k][c] * wih[d][c];  layout [s][d=384][k=128],
// emitted as bf16 hi/lo planes. 294,912 outputs, 128-MAC loop each (L2-hot).
// ---------------------------------------------------------------------------
__global__ __launch_bounds__(256) void k_combine(
    const float* __restrict__ gw, const float* __restrict__ wih,
    unsigned short* __restrict__ WcH, unsigned short* __restrict__ WcL) {
  int i = blockIdx.x * 256 + threadIdx.x;  // < 294912
  int s = i / 49152;
  int r = i % 49152;
  int d = r >> 7, k = r & 127;
  const float4* ga = (const float4*)&gw[(s << 14) + k * 128];
  const float4* wa = (const float4*)&wih[d * 128];
  float4 av = make_float4(0.f, 0.f, 0.f, 0.f);
#pragma unroll 8
  for (int c = 0; c < 32; c++) {
    float4 g4 = ga[c], w4 = wa[c];
    av.x += g4.x * w4.x; av.y += g4.y * w4.y;
    av.z += g4.z * w4.z; av.w += g4.w * w4.w;
  }
  float acc = (av.x + av.y) + (av.z + av.w);
  unsigned short h_ = f2bf(acc);
  WcH[i] = h_;
  WcL[i] = f2bf(acc - bf2f(h_));
}

// ---------------------------------------------------------------------------
// x -> bf16 hi/lo planes (once per launch); 8 elems/thread, 16B stores.
// ---------------------------------------------------------------------------
__global__ __launch_bounds__(256) void k_castx(const float* __restrict__ x,
                                               unsigned short* __restrict__ xH,
                                               unsigned short* __restrict__ xL) {
  int i = blockIdx.x * 256 + threadIdx.x;  // 1,048,576 threads x 8 elems
  const float4* x4 = (const float4*)x;
  float4 a = x4[i * 2 + 0];
  float4 b = x4[i * 2 + 1];
  uint2 ha = pack4bf(a, 0), hb = pack4bf(b, 0);
  uint2 la = pack4bf(a, 1), lb = pack4bf(b, 1);
  uint4 hv; hv.x = ha.x; hv.y = ha.y; hv.z = hb.x; hv.w = hb.y;
  uint4 lv; lv.x = la.x; lv.y = la.y; lv.z = lb.x; lv.w = lb.y;
  *(uint4*)&xH[i * 8] = hv;
  *(uint4*)&xL[i * 8] = lv;
}

// ---------------------------------------------------------------------------
// CSR build (by dst) so the per-step aggregation is an atomic-free gather
// ---------------------------------------------------------------------------
__global__ __launch_bounds__(256) void k_hist(const int* __restrict__ dst, int* __restrict__ cnt) {
  int e = blockIdx.x * 256 + threadIdx.x;
  if (e < EE) atomicAdd(&cnt[dst[e]], 1);
}

__global__ __launch_bounds__(1024) void k_scan(const int* __restrict__ cnt,
                                               int* __restrict__ rowptr,
                                               int* __restrict__ cursor) {
  __shared__ int part[1024];
  int t = threadIdx.x;
  int base = t * 64;
  int s = 0;
  for (int i = 0; i < 64; i++) s += cnt[base + i];
  part[t] = s;
  __syncthreads();
  for (int off = 1; off < 1024; off <<= 1) {
    int v = part[t];
    int u = (t >= off) ? part[t - off] : 0;
    __syncthreads();
    part[t] = v + u;
    __syncthreads();
  }
  int run = part[t] - s;  // exclusive prefix of this chunk
  for (int i = 0; i < 64; i++) {
    rowptr[base + i] = run;
    cursor[base + i] = run;
    run += cnt[base + i];
  }
  if (t == 1023) rowptr[NN] = run;
}

__global__ __launch_bounds__(256) void k_fill(const int* __restrict__ src,
                                              const int* __restrict__ dst,
                                              const float* __restrict__ ew,
                                              int* __restrict__ cursor,
                                              int* __restrict__ col,
                                              float* __restrict__ wgt) {
  int e = blockIdx.x * 256 + threadIdx.x;
  if (e < EE) {
    int d = dst[e];
    int p = atomicAdd(&cursor[d], 1);
    col[p] = src[e];
    wgt[p] = ew[e];
  }
}

// ---------------------------------------------------------------------------
// aggpre[n,:] = sum over in-edges of h[src,:]*w, reading h as bf16 hi/lo
// planes (hi+lo reconstruct, exact). 32 lanes/node x 4 channels each,
// 8 nodes/block, 4-edge unroll (avg degree 4 -> 16 loads in flight).
// Emits aggpre as bf16 hi/lo planes (GRU A-operand format).
// ---------------------------------------------------------------------------
__device__ __forceinline__ void acc_edge(const unsigned short* __restrict__ hH,
                                         const unsigned short* __restrict__ hL,
                                         int cA, int cb, float wA,
                                         float& ax, float& ay, float& az, float& aw) {
  uint2 h_ = *(const uint2*)&hH[cA * 128 + cb];
  uint2 l_ = *(const uint2*)&hL[cA * 128 + cb];
  float a0 = __uint_as_float(h_.x << 16) + __uint_as_float(l_.x << 16);
  float a1 = __uint_as_float(h_.x & 0xFFFF0000u) + __uint_as_float(l_.x & 0xFFFF0000u);
  float a2 = __uint_as_float(h_.y << 16) + __uint_as_float(l_.y << 16);
  float a3 = __uint_as_float(h_.y & 0xFFFF0000u) + __uint_as_float(l_.y & 0xFFFF0000u);
  ax += a0 * wA; ay += a1 * wA; az += a2 * wA; aw += a3 * wA;
}

__global__ __launch_bounds__(256) void k_gather(
    const unsigned short* __restrict__ hH, const unsigned short* __restrict__ hL,
    const int* __restrict__ rowptr, const int* __restrict__ col,
    const float* __restrict__ wgt,
    unsigned short* __restrict__ aggH, unsigned short* __restrict__ aggL) {
  int t = threadIdx.x;
  int n = blockIdx.x * 8 + (t >> 5);
  int cb = (t & 31) * 4;  // channel base
  int s0 = rowptr[n], s1 = rowptr[n + 1];
  float ax = 0.f, ay = 0.f, az = 0.f, aw = 0.f;
  int e = s0;
  for (; e + 4 <= s1; e += 4) {
    int cA = col[e], cB = col[e + 1], cC = col[e + 2], cD = col[e + 3];
    float wA = wgt[e], wB = wgt[e + 1], wC = wgt[e + 2], wD = wgt[e + 3];
    acc_edge(hH, hL, cA, cb, wA, ax, ay, az, aw);
    acc_edge(hH, hL, cB, cb, wB, ax, ay, az, aw);
    acc_edge(hH, hL, cC, cb, wC, ax, ay, az, aw);
    acc_edge(hH, hL, cD, cb, wD, ax, ay, az, aw);
  }
  for (; e < s1; e++) {
    acc_edge(hH, hL, col[e], cb, wgt[e], ax, ay, az, aw);
  }
  unsigned short h0 = f2bf(ax), h1 = f2bf(ay), h2 = f2bf(az), h3 = f2bf(aw);
  unsigned short l0 = f2bf(ax - bf2f(h0)), l1 = f2bf(ay - bf2f(h1));
  unsigned short l2 = f2bf(az - bf2f(h2)), l3 = f2bf(aw - bf2f(h3));
  uint2 hpk, lpk;
  hpk.x = (unsigned)h0 | ((unsigned)h1 << 16); hpk.y = (unsigned)h2 | ((unsigned)h3 << 16);
  lpk.x = (unsigned)l0 | ((unsigned)l1 << 16); lpk.y = (unsigned)l2 | ((unsigned)l3 << 16);
  int base = n * 128 + cb;
  *(uint2*)&aggH[base] = hpk;
  *(uint2*)&aggL[base] = lpk;
}

// ---------------------------------------------------------------------------
// Fused dual GEMM + GRU via split-bf16 MFMA (R1-exact structure). x-gates use
// the per-step COMBINED weight Wc_s = gw_s . wih^T (so no separate m=h@W GEMM
// exists). Both A matrices arrive as bf16 hi/lo planes -> staging is 8 exact
// 16B copies/thread. Output bf16 hi/lo planes; hold = hi+lo. grid (1024,2).
// ---------------------------------------------------------------------------
__global__ __launch_bounds__(256, 2) void k_gru_mfma(
    const unsigned short* __restrict__ aggH, const unsigned short* __restrict__ aggL,
    const unsigned short* __restrict__ hinH, const unsigned short* __restrict__ hinL,
    const unsigned short* __restrict__ wxh, const unsigned short* __restrict__ wxl,
    const unsigned short* __restrict__ whhCh, const unsigned short* __restrict__ whhCl,
    const float* __restrict__ bih, const float* __restrict__ bhh,
    unsigned short* __restrict__ houtH, unsigned short* __restrict__ houtL) {
  __shared__ __attribute__((aligned(16))) unsigned short As[2 * 64 * 136];  // [mat][row][k]
  int t = threadIdx.x;
  int r0 = blockIdx.x * 64;
  int d0 = blockIdx.y * 64;
  int wv = t >> 6, lane = t & 63;
  int ln = lane & 15, q = lane >> 4;
  f4acc acc[4][6];
#pragma unroll
  for (int mt = 0; mt < 4; mt++)
#pragma unroll
    for (int tg = 0; tg < 6; tg++) acc[mt][tg] = (f4acc)0.f;

  for (int p = 0; p < 3; p++) {
    if (p != 1) {  // stage both A mats full K: hi at p0, lo at p2
      const unsigned short* s0 = (p == 2) ? aggL : aggH;
      const unsigned short* s1 = (p == 2) ? hinL : hinH;
      if (p) __syncthreads();
#pragma unroll
      for (int it = 0; it < 8; it++) {
        int v8 = it * 256 + t;          // 0..2047
        int mat = v8 >> 10;
        int row = (v8 >> 4) & 63, k = (v8 & 15) * 8;
        const unsigned short* S = mat ? s1 : s0;
        *(uint4*)&As[mat * 8704 + row * 136 + k] = *(const uint4*)&S[(r0 + row) * 128 + k];
      }
      __syncthreads();
    }
    const unsigned short* wx = (p == 1) ? wxl : wxh;
    const unsigned short* wh = (p == 1) ? whhCl : whhCh;
#pragma unroll
    for (int k0 = 0; k0 < 128; k0 += 32) {
      s8bf af[2][4], bfr[6];
#pragma unroll
      for (int tg = 0; tg < 6; tg++) {
        int gate = (tg < 3) ? tg : tg - 3;
        const unsigned short* W = (tg < 3) ? wx : wh;
        bfr[tg] = *(const s8bf*)&W[(gate * 128 + d0 + wv * 16 + ln) * 128 + k0 + q * 8];
      }
#pragma unroll
      for (int mat = 0; mat < 2; mat++)
#pragma unroll
        for (int mt = 0; mt < 4; mt++)
          af[mat][mt] = *(const s8bf*)&As[mat * 8704 + (mt * 16 + ln) * 136 + k0 + q * 8];
#pragma unroll
      for (int mt = 0; mt < 4; mt++)
#pragma unroll
        for (int tg = 0; tg < 6; tg++)
          acc[mt][tg] = __builtin_amdgcn_mfma_f32_16x16x32_bf16(
              af[tg < 3 ? 0 : 1][mt], bfr[tg], acc[mt][tg], 0, 0, 0);
    }
  }
  int d = d0 + wv * 16 + ln;
  float bi0 = bih[d], bi1 = bih[128 + d], bi2 = bih[256 + d];
  float bh0 = bhh[d], bh1 = bhh[128 + d], bh2 = bhh[256 + d];
#pragma unroll
  for (int mt = 0; mt < 4; mt++) {
#pragma unroll
    for (int reg = 0; reg < 4; reg++) {
      int r = r0 + mt * 16 + q * 4 + reg;
      int idx = r * 128 + d;
      float hold = bf2f(hinH[idx]) + bf2f(hinL[idx]);
      float xr = acc[mt][0][reg] + bi0;
      float xz = acc[mt][1][reg] + bi1;
      float xn = acc[mt][2][reg] + bi2;
      float hr = acc[mt][3][reg] + bh0;
      float hz = acc[mt][4][reg] + bh1;
      float hn = acc[mt][5][reg] + bh2;
      float rr = 1.f / (1.f + expf(-(xr + hr)));
      float zz = 1.f / (1.f + expf(-(xz + hz)));
      float nnv = tanhf(xn + rr * hn);
      float hv = (1.f - zz) * nnv + zz * hold;
      unsigned short hh = f2bf(hv);
      houtH[idx] = hh;
      houtL[idx] = f2bf(hv - bf2f(hh));
    }
  }
}

// ---------------------------------------------------------------------------
// Generic implicit-GEMM conv via split-bf16 MFMA. (R1-exact structure —
// measured best: full-K staging, NT=2, 1-deep B prefetch, 64x128 block.)
// Inputs pre-split bf16 hi/lo planes (plane A ch<WA, plane B ch>=WA).
// Weights [tap][co][ci] bf16 hi/lo. Output [g][Lco][CIN] f32 + per-co stats.
// Block: 64 l-rows x 128 co; grid (ceil(Lco/64), CIN/128, G).
// ---------------------------------------------------------------------------
template<int CIN, int TAPS, int WA>
__global__ __launch_bounds__(256, 4) void k_conv_mfma(
    const unsigned short* __restrict__ hiA, const unsigned short* __restrict__ hiB,
    const unsigned short* __restrict__ loA, const unsigned short* __restrict__ loB,
    const unsigned short* __restrict__ Wh, const unsigned short* __restrict__ Wl,
    const float* __restrict__ bias, float* __restrict__ out,
    float* __restrict__ stats, int Lin, int Lco) {
  constexpr int APAD = CIN + 8;
  constexpr int ROWS = 64 + TAPS - 1;
  constexpr int NCH = CIN / 32;
  constexpr int TOT8 = ROWS * CIN / 8;       // 16B chunks to stage
  constexpr int NIT = (TOT8 + 255) / 256;
  constexpr int NINNER = TAPS * NCH;
  __shared__ __attribute__((aligned(16))) unsigned short As[ROWS * APAD];
  __shared__ float sred[256];
  const int g = blockIdx.z, co0 = blockIdx.y * 128, l0 = blockIdx.x * 64;
  const int t = threadIdx.x;
  const int wv = t >> 6, lane = t & 63, ln = lane & 15, q = lane >> 4;
  f4acc acc[4][2];
#pragma unroll
  for (int mt = 0; mt < 4; mt++)
#pragma unroll
    for (int nt = 0; nt < 2; nt++) acc[mt][nt] = (f4acc)0.f;

  // pass order: (Ah,Bh), (Ah,Bl), (Al,Bh)
  for (int p = 0; p < 3; p++) {
    if (p != 1) {
      const unsigned short* pA = (p == 2) ? loA : hiA;
      const unsigned short* pB = (p == 2) ? loB : hiB;
      if (p) __syncthreads();
#pragma unroll
      for (int it = 0; it < NIT; it++) {
        int v8 = it * 256 + t;
        if (NIT * 256 == TOT8 || v8 < TOT8) {
          int row = (v8 * 8) / CIN, ch = (v8 * 8) % CIN;
          int lr = l0 + row; if (lr > Lin - 1) lr = Lin - 1;
          uint4 v;
          if (ch < WA) v = *(const uint4*)&pA[(g * Lin + lr) * WA + ch];
          else         v = *(const uint4*)&pB[(g * Lin + lr) * WA + ch - WA];
          *(uint4*)&As[row * APAD + ch] = v;
        }
      }
      __syncthreads();
    }
    const unsigned short* W = (p == 1) ? Wl : Wh;
    // flat (tap, ch) loop with 1-deep B prefetch (B loads are the latency pole)
    s8bf bcur[2], bnxt[2];
#pragma unroll
    for (int nt = 0; nt < 2; nt++)
      bcur[nt] = *(const s8bf*)&W[(co0 + wv * 32 + nt * 16 + ln) * CIN + q * 8];
#pragma unroll
    for (int it = 0; it < NINNER; it++) {
      const int tap = it / NCH, ch = it % NCH;
      if (it + 1 < NINNER) {
        const int ntap = (it + 1) / NCH, nch = (it + 1) % NCH;
#pragma unroll
        for (int nt = 0; nt < 2; nt++)
          bnxt[nt] = *(const s8bf*)&W[(ntap * CIN + co0 + wv * 32 + nt * 16 + ln) * CIN + nch * 32 + q * 8];
      }
      const int c0 = ch * 32;
      s8bf af[4];
#pragma unroll
      for (int mt = 0; mt < 4; mt++)
        af[mt] = *(const s8bf*)&As[(mt * 16 + ln + tap) * APAD + c0 + q * 8];
#pragma unroll
      for (int mt = 0; mt < 4; mt++)
#pragma unroll
        for (int nt = 0; nt < 2; nt++)
          acc[mt][nt] = __builtin_amdgcn_mfma_f32_16x16x32_bf16(af[mt], bcur[nt], acc[mt][nt], 0, 0, 0);
      if (it + 1 < NINNER) { bcur[0] = bnxt[0]; bcur[1] = bnxt[1]; }
    }
  }
  // epilogue: bias, store [g][l][co], per-co sum/sumsq
  sred[t] = 0.f;
  __syncthreads();
#pragma unroll
  for (int nt = 0; nt < 2; nt++) {
    int cl = wv * 32 + nt * 16 + ln;
    int co = co0 + cl;
    float bv = bias[co];
    float s = 0.f, s2 = 0.f;
#pragma unroll
    for (int mt = 0; mt < 4; mt++)
#pragma unroll
      for (int reg = 0; reg < 4; reg++) {
        int l = l0 + mt * 16 + q * 4 + reg;
        if (l < Lco) {
          float v = acc[mt][nt][reg] + bv;
          out[(g * Lco + l) * CIN + co] = v;
          s += v; s2 += v * v;
        }
      }
    atomicAdd(&sred[cl], s);
    atomicAdd(&sred[128 + cl], s2);
  }
  __syncthreads();
  if (t < 128) atomicAdd(&stats[co0 + t], sred[t]);
  else atomicAdd(&stats[CIN + co0 + (t - 128)], sred[t]);
}

// ---------------------------------------------------------------------------
// BN(training stats) -> ReLU -> maxpool(pk, stride 2); l-major both sides.
// Vectorized 4 channels/thread (16B in-loads; 8B plane writes / 16B f32 write).
// Per-element math bit-identical to the scalar version.
// PLANES=true: emit bf16 hi/lo planes; PLANES=false: emit f32.
// ---------------------------------------------------------------------------
template<bool PLANES>
__global__ __launch_bounds__(256) void k_bnpool(const float* __restrict__ in,
                                                float* __restrict__ outF,
                                                unsigned short* __restrict__ outH,
                                                unsigned short* __restrict__ outL,
                                                const float* __restrict__ stats,
                                                const float* __restrict__ gamma,
                                                const float* __restrict__ beta,
                                                int Cch, int LinC, int Lout, int pk) {
  int idx = blockIdx.x * 256 + threadIdx.x;
  int c4n = Cch >> 2;
  int total = GG * c4n * Lout;
  if (idx >= total) return;
  int c = (idx % c4n) * 4;
  int r = idx / c4n;
  int p = r % Lout;
  int g = r / Lout;
  float cntf = (float)(GG * LinC);
  float4 st0 = *(const float4*)&stats[c];
  float4 st1 = *(const float4*)&stats[Cch + c];
  float4 gm = *(const float4*)&gamma[c];
  float4 bt = *(const float4*)&beta[c];
  float4 inv, sh;
  {
    float m0 = st0.x / cntf, m1 = st0.y / cntf, m2 = st0.z / cntf, m3 = st0.w / cntf;
    inv.x = rsqrtf(st1.x / cntf - m0 * m0 + 1e-5f) * gm.x;
    inv.y = rsqrtf(st1.y / cntf - m1 * m1 + 1e-5f) * gm.y;
    inv.z = rsqrtf(st1.z / cntf - m2 * m2 + 1e-5f) * gm.z;
    inv.w = rsqrtf(st1.w / cntf - m3 * m3 + 1e-5f) * gm.w;
    sh.x = bt.x - m0 * inv.x; sh.y = bt.y - m1 * inv.y;
    sh.z = bt.z - m2 * inv.z; sh.w = bt.w - m3 * inv.w;
  }
  const float* base = &in[((g * LinC) + 2 * p) * Cch + c];
  float4 m = make_float4(0.f, 0.f, 0.f, 0.f);  // relu output >= 0
  for (int k = 0; k < pk; k++) {
    float4 v = *(const float4*)&base[k * Cch];
    m.x = fmaxf(m.x, fmaxf(v.x * inv.x + sh.x, 0.f));
    m.y = fmaxf(m.y, fmaxf(v.y * inv.y + sh.y, 0.f));
    m.z = fmaxf(m.z, fmaxf(v.z * inv.z + sh.z, 0.f));
    m.w = fmaxf(m.w, fmaxf(v.w * inv.w + sh.w, 0.f));
  }
  int o = (g * Lout + p) * Cch + c;
  if (PLANES) {
    *(uint2*)&outH[o] = pack4bf(m, 0);
    *(uint2*)&outL[o] = pack4bf(m, 1);
  } else {
    *(float4*)&outF[o] = m;
  }
}

// ---------------------------------------------------------------------------
// final: Y2 [g][127][128], Z2 [g][127][256] l-major f32. Coalesced rewrite:
// 4 rows per block-iteration (1 row/wave), each wave's 64 lanes load
// contiguous float2 (Y) / float4 (Z) chunks, butterfly shuffle-reduce the
// 4 dot products, product + accumulate per wave; LDS-combine 4 waves.
// ---------------------------------------------------------------------------
__global__ __launch_bounds__(256) void k_final(const float* __restrict__ Y2,
                                               const float* __restrict__ Z2,
                                               const float* __restrict__ myw,
                                               const float* __restrict__ myb,
                                               const float* __restrict__ mzw,
                                               const float* __restrict__ mzb,
                                               float* __restrict__ outp) {
  __shared__ float red0[4];
  __shared__ float red1[4];
  int g = blockIdx.x;
  int t = threadIdx.x;
  int wv = t >> 6, lane = t & 63;
  // per-lane weight chunks
  float2 wy0 = *(const float2*)&myw[lane * 2];
  float2 wy1 = *(const float2*)&myw[128 + lane * 2];
  float4 wz0 = *(const float4*)&mzw[lane * 4];
  float4 wz1 = *(const float4*)&mzw[256 + lane * 4];
  float yb0 = myb[0], yb1 = myb[1], zb0 = mzb[0], zb1 = mzb[1];
  float acc0 = 0.f, acc1 = 0.f;
  for (int l = wv; l < P2; l += 4) {
    float2 yv = *(const float2*)&Y2[(g * P2 + l) * 128 + lane * 2];
    float4 zv = *(const float4*)&Z2[(g * P2 + l) * 256 + lane * 4];
    float y0 = yv.x * wy0.x + yv.y * wy0.y;
    float y1 = yv.x * wy1.x + yv.y * wy1.y;
    float z0 = zv.x * wz0.x + zv.y * wz0.y + zv.z * wz0.z + zv.w * wz0.w;
    float z1 = zv.x * wz1.x + zv.y * wz1.y + zv.z * wz1.z + zv.w * wz1.w;
#pragma unroll
    for (int off = 32; off > 0; off >>= 1) {
      y0 += __shfl_xor(y0, off);
      y1 += __shfl_xor(y1, off);
      z0 += __shfl_xor(z0, off);
      z1 += __shfl_xor(z1, off);
    }
    acc0 += (y0 + yb0) * (z0 + zb0);
    acc1 += (y1 + yb1) * (z1 + zb1);
  }
  if (lane == 0) { red0[wv] = acc0; red1[wv] = acc1; }
  __syncthreads();
  if (t == 0) {
    outp[g * 2 + 0] = (red0[0] + red0[1] + red0[2] + red0[3]) / 127.f;
    outp[g * 2 + 1] = (red1[0] + red1[1] + red1[2] + red1[3]) / 127.f;
  }
}

// ---------------------------------------------------------------------------
extern "C" void kernel_launch(void* const* d_in, const int* in_sizes, int n_in,
                              void* d_out, int out_size, void* d_ws, size_t ws_size,
                              hipStream_t stream) {
  const float* x   = (const float*)d_in[0];
  const int* ei    = (const int*)d_in[1];
  const float* ew  = (const float*)d_in[2];
  // d_in[3] = batch: arange(N)//L -> pure reshape, unused
  const float* gw  = (const float*)d_in[4];
  const float* wih = (const float*)d_in[5];
  const float* whh = (const float*)d_in[6];
  const float* bih = (const float*)d_in[7];
  const float* bhh = (const float*)d_in[8];
  const float* w1  = (const float*)d_in[9];
  const float* b1  = (const float*)d_in[10];
  const float* w2  = (const float*)d_in[11];
  const float* b2  = (const float*)d_in[12];
  const float* wc1 = (const float*)d_in[13];
  const float* bc1 = (const float*)d_in[14];
  const float* wc2 = (const float*)d_in[15];
  const float* bc2 = (const float*)d_in[16];
  const float* bn1g = (const float*)d_in[17];
  const float* bn1b = (const float*)d_in[18];
  const float* bn2g = (const float*)d_in[19];
  const float* bn2b = (const float*)d_in[20];
  const float* myw = (const float*)d_in[21];
  const float* myb = (const float*)d_in[22];
  const float* mzw = (const float*)d_in[23];
  const float* mzb = (const float*)d_in[24];
  float* out = (float*)d_out;

  // ---------------- workspace layout ----------------
  // Persistent region (lives across GGNN + conv phases):
  float* ws = (float*)d_ws;
  unsigned short* PH = (unsigned short*)ws;       // 8,388,608 us (h planes, ping; final h)
  unsigned short* PL = PH + 8388608;
  unsigned short* xH = PL + 8388608;              // x planes
  unsigned short* xL = xH + 8388608;
  unsigned short* c1h  = xL + 8388608;            // conv weights bf16
  unsigned short* c1l  = c1h + 49152;
  unsigned short* cc1h = c1l + 49152;
  unsigned short* cc1l = cc1h + 196608;
  unsigned short* c2h  = cc1l + 196608;
  unsigned short* c2l  = c2h + 16384;
  unsigned short* cc2h = c2l + 16384;
  unsigned short* cc2l = cc2h + 65536;
  float* stats = (float*)(cc2l + 65536);          // 512 f
  float* Y2 = stats + 512;                        // 2,080,768 f ([g][127][128] f32)
  float* Z2 = Y2 + 2080768;                       // 4,161,536 f ([g][127][256] f32)
  float* shared0 = Z2 + 4161536;
  // GGNN-phase view of shared region:
  unsigned short* QH = (unsigned short*)shared0;  // h planes, pong
  unsigned short* QL = QH + 8388608;
  unsigned short* WcCh = QL + 8388608;            // combined x-gate weights: 6 x [384][128]
  unsigned short* WcCl = WcCh + 294912;
  unsigned short* aggH = WcCl + 294912;           // aggpre planes
  unsigned short* aggL = aggH + 8388608;
  unsigned short* whhCh = aggL + 8388608;         // GRU h-gate weights bf16
  unsigned short* whhCl = whhCh + 49152;
  int* cnt    = (int*)(whhCl + 49152);            // 65,536
  int* rowptr = cnt + 65536;                      // 65,537
  int* cursor = rowptr + 65537;                   // 65,536
  int* col    = cursor + 65536;                   // 262,144
  float* wgt  = (float*)(col + 262144);           // 262,144
  float* ggnn_end = wgt + 262144;
  // Conv-phase view of shared region (aliases GGNN buffers, all dead by then):
  float* bufA = shared0;                          // 16,711,680 f (conv out, l-major)
  unsigned short* bufBH = (unsigned short*)(bufA + 16711680);  // pool1 planes
  unsigned short* bufBL = bufBH + 8323072;
  float* conv_end = (float*)(bufBL + 8323072);
  float* wend = (ggnn_end > conv_end) ? ggnn_end : conv_end;
  size_t needed = (size_t)(wend - ws) * 4;
  if (ws_size < needed) return;

  const int* src = ei;
  const int* dst = ei + EE;

  // one-time prep per launch
  k_prep<<<768, 256, 0, stream>>>(wih, whh, gw, w1, wc1, w2, wc2,
                                  whhCh, whhCl,
                                  c1h, c1l, cc1h, cc1l, c2h, c2l, cc2h, cc2l);
  k_combine<<<1152, 256, 0, stream>>>(gw, wih, WcCh, WcCl);
  k_castx<<<4096, 256, 0, stream>>>(x, xH, xL);
  hipMemsetAsync(cnt, 0, 65536 * 4, stream);
  k_hist<<<1024, 256, 0, stream>>>(dst, cnt);
  k_scan<<<1, 1024, 0, stream>>>(cnt, rowptr, cursor);
  k_fill<<<1024, 256, 0, stream>>>(src, dst, ew, cursor, col, wgt);

  // GGNN: 6 steps, ping-pong h planes. The per-step m=h@W GEMM is folded
  // into the GRU x-gate weight (Wc_s), so each step is gather + GRU only.
  for (int s = 0; s < NSTEPS; s++) {
    const unsigned short* AH = (s == 0) ? xH : ((s & 1) ? QH : PH);
    const unsigned short* AL = (s == 0) ? xL : ((s & 1) ? QL : PL);
    unsigned short* OH = (s & 1) ? PH : QH;
    unsigned short* OL = (s & 1) ? PL : QL;
    k_gather<<<8192, 256, 0, stream>>>(AH, AL, rowptr, col, wgt, aggH, aggL);
    k_gru_mfma<<<dim3(1024, 2), 256, 0, stream>>>(aggH, aggL, AH, AL,
                                                  WcCh + s * 49152, WcCl + s * 49152,
                                                  whhCh, whhCl, bih, bhh, OH, OL);
  }

  // Y path: conv3 -> bufA [g][510][128]; pool -> bufB planes [g][254][128];
  //         1x1 -> bufA [g][254][128]; pool -> Y2 f32 [g][127][128]
  hipMemsetAsync(stats, 0, 512 * 4, stream);
  k_conv_mfma<128, 3, 128><<<dim3(8, 1, 128), 256, 0, stream>>>(
      PH, nullptr, PL, nullptr, c1h, c1l, b1, bufA, stats, 512, L1);
  k_bnpool<true><<<(GG * 128 * P1 / 4 + 255) / 256, 256, 0, stream>>>(
      bufA, nullptr, bufBH, bufBL, stats, bn1g, bn1b, 128, L1, P1, 3);
  hipMemsetAsync(stats, 0, 512 * 4, stream);
  k_conv_mfma<128, 1, 128><<<dim3(4, 1, 128), 256, 0, stream>>>(
      bufBH, nullptr, bufBL, nullptr, c2h, c2l, b2, bufA, stats, P1, P1);
  k_bnpool<false><<<(GG * 128 * P2 / 4 + 255) / 256, 256, 0, stream>>>(
      bufA, Y2, nullptr, nullptr, stats, bn1g, bn1b, 128, P1, P2, 2);

  // Z path: conv3(concat h,x) -> bufA [g][510][256]; pool -> bufB planes;
  //         1x1 -> bufA [g][254][256]; pool -> Z2 f32 [g][127][256]
  hipMemsetAsync(stats, 0, 512 * 4, stream);
  k_conv_mfma<256, 3, 128><<<dim3(8, 2, 128), 256, 0, stream>>>(
      PH, xH, PL, xL, cc1h, cc1l, bc1, bufA, stats, 512, L1);
  k_bnpool<true><<<(GG * 256 * P1 / 4 + 255) / 256, 256, 0, stream>>>(
      bufA, nullptr, bufBH, bufBL, stats, bn2g, bn2b, 256, L1, P1, 3);
  hipMemsetAsync(stats, 0, 512 * 4, stream);
  k_conv_mfma<256, 1, 256><<<dim3(4, 2, 128), 256, 0, stream>>>(
      bufBH, nullptr, bufBL, nullptr, cc2h, cc2l, bc2, bufA, stats, P1, P1);
  k_bnpool<false><<<(GG * 256 * P2 / 4 + 255) / 256, 256, 0, stream>>>(
      bufA, Z2, nullptr, nullptr, stats, bn2g, bn2b, 256, P1, P2, 2);

  // epilogue
  k_final<<<128, 256, 0, stream>>>(Y2, Z2, myw, myb, mzw, mzb, out);
}